// Round 1
// 5617.307 us; speedup vs baseline: 1.3604x; 1.3604x over previous
//
#include <hip/hip_runtime.h>
#include <math.h>

#define Hh 128
#define Ww 256
#define Dd 768
#define NPLANE 256            // B*H
#define WF 129                // W/2+1
#define SFREQ (WF*Dd)         // 99072
#define NPOS (2*Hh*WF)        // 33024
#define LAMBDA_SS 0.01f

typedef short short8 __attribute__((ext_vector_type(8)));
typedef float floatx4 __attribute__((ext_vector_type(4)));

__device__ __forceinline__ float bf2f(ushort u) {
    union { unsigned int i; float f; } v; v.i = ((unsigned int)u) << 16; return v.f;
}
__device__ __forceinline__ ushort f2bf(float f) {
    union { float f; unsigned int i; } v; v.f = f;
    unsigned int r = v.i + 0x7fffu + ((v.i >> 16) & 1u);   // RTNE
    return (ushort)(r >> 16);
}
__device__ __forceinline__ short8 neg8(short8 a) {        // flip bf16 sign bits
    union { short8 s; unsigned int u[4]; } v; v.s = a;
    v.u[0] ^= 0x80008000u; v.u[1] ^= 0x80008000u;
    v.u[2] ^= 0x80008000u; v.u[3] ^= 0x80008000u;
    return v.s;
}

// ------------------------------------------------- LayerNorm: fp32 in, bf16 out
__global__ __launch_bounds__(256) void ln_kernel(const float* __restrict__ x,
        const float* __restrict__ g, const float* __restrict__ b,
        ushort* __restrict__ out) {
    int row = blockIdx.x;
    int tid = threadIdx.x;
    const float* xr = x + (size_t)row * Dd;
    float v0 = xr[tid], v1 = xr[tid + 256], v2 = xr[tid + 512];
    __shared__ float red[256];
    red[tid] = v0 + v1 + v2;
    __syncthreads();
    for (int o = 128; o > 0; o >>= 1) { if (tid < o) red[tid] += red[tid + o]; __syncthreads(); }
    float mean = red[0] * (1.0f / 768.0f);
    __syncthreads();
    float d0 = v0 - mean, d1 = v1 - mean, d2 = v2 - mean;
    red[tid] = d0 * d0 + d1 * d1 + d2 * d2;
    __syncthreads();
    for (int o = 128; o > 0; o >>= 1) { if (tid < o) red[tid] += red[tid + o]; __syncthreads(); }
    float inv = rsqrtf(red[0] * (1.0f / 768.0f) + 1e-5f);
    ushort* orow = out + (size_t)row * Dd;
    orow[tid]       = f2bf(d0 * inv * g[tid]       + b[tid]);
    orow[tid + 256] = f2bf(d1 * inv * g[tid + 256] + b[tid + 256]);
    orow[tid + 512] = f2bf(d2 * inv * g[tid + 512] + b[tid + 512]);
}

// ------------------------------------------------- forward real DFT along W
__global__ __launch_bounds__(256) void dft_w_fwd_kernel(const ushort* __restrict__ X,
        ushort* __restrict__ Fr, ushort* __restrict__ Fi) {
    int d = blockIdx.x * 256 + threadIdx.x;
    int wf0 = blockIdx.y * 4;
    int p = blockIdx.z;
    const ushort* xp = X + (size_t)p * Ww * Dd + d;
    float twr[4], twi[4], sr[4], si[4], ar[4], ai[4];
#pragma unroll
    for (int q = 0; q < 4; ++q) {
        float ang = (float)(-2.0 * M_PI * (double)(wf0 + q) / 256.0);
        sincosf(ang, &si[q], &sr[q]);
        twr[q] = 1.0f; twi[q] = 0.0f; ar[q] = 0.0f; ai[q] = 0.0f;
    }
    for (int w = 0; w < Ww; ++w) {
        float xv = bf2f(xp[(size_t)w * Dd]);
#pragma unroll
        for (int q = 0; q < 4; ++q) {
            ar[q] += xv * twr[q];
            ai[q] += xv * twi[q];
            float nr = twr[q] * sr[q] - twi[q] * si[q];
            twi[q]  = twr[q] * si[q] + twi[q] * sr[q];
            twr[q]  = nr;
        }
    }
#pragma unroll
    for (int q = 0; q < 4; ++q) {
        int wf = wf0 + q;
        if (wf < WF) {
            size_t o = (size_t)p * SFREQ + (size_t)wf * Dd + d;
            Fr[o] = f2bf(ar[q] * 0.0625f);
            Fi[o] = f2bf(ai[q] * 0.0625f);
        }
    }
}

// ------------------------------------------- complex DFT along H (fwd/inv)
__global__ __launch_bounds__(256) void dft_h_kernel(const ushort* __restrict__ Ir,
        const ushort* __restrict__ Ii, ushort* __restrict__ Or, ushort* __restrict__ Oi,
        float sign) {
    int col = blockIdx.x * 256 + threadIdx.x;
    int hf0 = blockIdx.y * 4;
    int b = blockIdx.z;
    const ushort* ir = Ir + (size_t)b * Hh * SFREQ + col;
    const ushort* ii = Ii + (size_t)b * Hh * SFREQ + col;
    float twr[4], twi[4], sr[4], si[4], ar[4], ai[4];
#pragma unroll
    for (int q = 0; q < 4; ++q) {
        float ang = sign * (float)(2.0 * M_PI * (double)(hf0 + q) / 128.0);
        sincosf(ang, &si[q], &sr[q]);
        twr[q] = 1.0f; twi[q] = 0.0f; ar[q] = 0.0f; ai[q] = 0.0f;
    }
    for (int h = 0; h < Hh; ++h) {
        float vr = bf2f(ir[(size_t)h * SFREQ]);
        float vi = bf2f(ii[(size_t)h * SFREQ]);
#pragma unroll
        for (int q = 0; q < 4; ++q) {
            ar[q] += vr * twr[q] - vi * twi[q];
            ai[q] += vr * twi[q] + vi * twr[q];
            float nr = twr[q] * sr[q] - twi[q] * si[q];
            twi[q]  = twr[q] * si[q] + twi[q] * sr[q];
            twr[q]  = nr;
        }
    }
    const float sc = 0.08838834764831845f;  // 1/sqrt(128)
#pragma unroll
    for (int q = 0; q < 4; ++q) {
        size_t o = (size_t)b * Hh * SFREQ + (size_t)(hf0 + q) * SFREQ + col;
        Or[o] = f2bf(ar[q] * sc);
        Oi[o] = f2bf(ai[q] * sc);
    }
}

// --------------------------------------------- inverse real DFT along W
__global__ __launch_bounds__(256) void dft_w_inv_kernel(const ushort* __restrict__ Hr,
        const ushort* __restrict__ Hi, float* __restrict__ out) {
    int d = blockIdx.x * 256 + threadIdx.x;
    int w0 = blockIdx.y * 4;
    int p = blockIdx.z;
    const ushort* hr_ = Hr + (size_t)p * SFREQ + d;
    const ushort* hi_ = Hi + (size_t)p * SFREQ + d;
    float twr[4], twi[4], sr[4], si[4], acc[4];
#pragma unroll
    for (int q = 0; q < 4; ++q) {
        float ang = (float)(2.0 * M_PI * (double)(w0 + q) / 256.0);
        sincosf(ang, &si[q], &sr[q]);
        twr[q] = 1.0f; twi[q] = 0.0f; acc[q] = 0.0f;
    }
    for (int wf = 0; wf < WF; ++wf) {
        float vr = bf2f(hr_[(size_t)wf * Dd]);
        float vi = bf2f(hi_[(size_t)wf * Dd]);
        float wt = (wf == 0 || wf == 128) ? 0.5f : 1.0f;
        vr *= wt; vi *= wt;
#pragma unroll
        for (int q = 0; q < 4; ++q) {
            acc[q] += vr * twr[q] - vi * twi[q];
            float nr = twr[q] * sr[q] - twi[q] * si[q];
            twi[q]  = twr[q] * si[q] + twi[q] * sr[q];
            twr[q]  = nr;
        }
    }
#pragma unroll
    for (int q = 0; q < 4; ++q)
        out[(size_t)p * Ww * Dd + (size_t)(w0 + q) * Dd + d] = acc[q] * 0.125f;
}

// ------------------------------------------ mix weight prep: fp32 [ri][l][m][n]
// -> bf16 Bt layout [ri][l][n][m]  (16 matrices of 96x96 per tensor)
__global__ __launch_bounds__(256) void wmix_prep_kernel(const float* __restrict__ w,
        ushort* __restrict__ wt) {
    int mat = blockIdx.x;              // 0..15 = ri*8 + l
    const float* src = w + (size_t)mat * 96 * 96;
    ushort* dst = wt + (size_t)mat * 96 * 96;
    for (int idx = threadIdx.x; idx < 96 * 96; idx += 256) {
        int n = idx / 96, m = idx - n * 96;
        dst[idx] = f2bf(src[(size_t)m * 96 + n]);
    }
}

// ------------------------------------------------- block-diag channel mixing (MFMA)
// Per block l: Or = act(Xr@Wr - Xi@Wi + br), Oi = act(Xr@Wi + Xi@Wr + bi)
// X: [NPOS][768] bf16 (block l occupies channels l*96..+95). Wt: bf16 [2][8][96(n)][96(m)].
// Workgroup = 128 positions x one l. 4 waves x 32 rows. K=96 in 3 steps of 32.
#define WSTR 104   // LDS row stride (shorts): 16B-aligned reads, start banks spread 8-way
__global__ __launch_bounds__(256) void mix_mfma_kernel(const ushort* __restrict__ Xr,
        const ushort* __restrict__ Xi, const ushort* __restrict__ Wt,
        const float* __restrict__ bias, ushort* __restrict__ Or,
        ushort* __restrict__ Oi, int shrink) {
    int l = blockIdx.y;
    int bm = blockIdx.x * 128;
    int tid = threadIdx.x;
    int wv = tid >> 6, lane = tid & 63;
    int quad = lane >> 4, l16 = lane & 15;

    __shared__ __align__(16) ushort Wr_s[96 * WSTR];
    __shared__ __align__(16) ushort Wi_s[96 * WSTR];
    const ushort* wr_g = Wt + (size_t)l * 96 * 96;
    const ushort* wi_g = Wt + (size_t)(8 + l) * 96 * 96;
    for (int idx = tid; idx < (96 * 96) / 4; idx += 256) {
        int n = idx / 24, mq = idx - n * 24;
        *(uint2*)&Wr_s[n * WSTR + mq * 4] = *(const uint2*)(wr_g + (size_t)n * 96 + mq * 4);
        *(uint2*)&Wi_s[n * WSTR + mq * 4] = *(const uint2*)(wi_g + (size_t)n * 96 + mq * 4);
    }

    floatx4 accr[2][6], acci[2][6];
#pragma unroll
    for (int i = 0; i < 2; ++i)
#pragma unroll
        for (int j = 0; j < 6; ++j) {
            accr[i][j][0] = 0.f; accr[i][j][1] = 0.f; accr[i][j][2] = 0.f; accr[i][j][3] = 0.f;
            acci[i][j][0] = 0.f; acci[i][j][1] = 0.f; acci[i][j][2] = 0.f; acci[i][j][3] = 0.f;
        }

    int row = bm + wv * 32 + l16;
    const ushort* agr = Xr + (size_t)row * 768 + l * 96;
    const ushort* agi = Xi + (size_t)row * 768 + l * 96;
    __syncthreads();

#pragma unroll
    for (int ks = 0; ks < 3; ++ks) {
        int ko = ks * 32 + quad * 8;
        // A fragments straight from global: wave covers rows 0-15 x 64 contiguous B -> coalesced
        short8 ar0 = *(const short8*)(agr + ko);
        short8 ar1 = *(const short8*)(agr + (size_t)16 * 768 + ko);
        short8 ai0 = *(const short8*)(agi + ko);
        short8 ai1 = *(const short8*)(agi + (size_t)16 * 768 + ko);
        short8 an0 = neg8(ai0), an1 = neg8(ai1);
#pragma unroll
        for (int j = 0; j < 6; ++j) {
            short8 br = *(const short8*)&Wr_s[(j * 16 + l16) * WSTR + ko];
            short8 bi = *(const short8*)&Wi_s[(j * 16 + l16) * WSTR + ko];
            accr[0][j] = __builtin_amdgcn_mfma_f32_16x16x32_bf16(ar0, br, accr[0][j], 0, 0, 0);
            accr[0][j] = __builtin_amdgcn_mfma_f32_16x16x32_bf16(an0, bi, accr[0][j], 0, 0, 0);
            acci[0][j] = __builtin_amdgcn_mfma_f32_16x16x32_bf16(ar0, bi, acci[0][j], 0, 0, 0);
            acci[0][j] = __builtin_amdgcn_mfma_f32_16x16x32_bf16(ai0, br, acci[0][j], 0, 0, 0);
            accr[1][j] = __builtin_amdgcn_mfma_f32_16x16x32_bf16(ar1, br, accr[1][j], 0, 0, 0);
            accr[1][j] = __builtin_amdgcn_mfma_f32_16x16x32_bf16(an1, bi, accr[1][j], 0, 0, 0);
            acci[1][j] = __builtin_amdgcn_mfma_f32_16x16x32_bf16(ar1, bi, acci[1][j], 0, 0, 0);
            acci[1][j] = __builtin_amdgcn_mfma_f32_16x16x32_bf16(ai1, br, acci[1][j], 0, 0, 0);
        }
    }

#pragma unroll
    for (int i = 0; i < 2; ++i) {
        int row0 = bm + wv * 32 + i * 16 + quad * 4;
#pragma unroll
        for (int j = 0; j < 6; ++j) {
            int col = j * 16 + l16;
            float bvr = bias[l * 96 + col];
            float bvi = bias[768 + l * 96 + col];
#pragma unroll
            for (int r = 0; r < 4; ++r) {
                float vr = accr[i][j][r] + bvr;
                float vi = acci[i][j][r] + bvi;
                if (shrink) { vr = fmaxf(vr - LAMBDA_SS, 0.0f); vi = fmaxf(vi - LAMBDA_SS, 0.0f); }
                else        { vr = fmaxf(vr, 0.0f);             vi = fmaxf(vi, 0.0f); }
                size_t o = (size_t)(row0 + r) * 768 + l * 96 + col;
                Or[o] = f2bf(vr);
                Oi[o] = f2bf(vi);
            }
        }
    }
}

// ------------------------------------- fp32 -> bf16 transpose [R][C] -> [C][R]
__global__ __launch_bounds__(256) void transpose_kernel(const float* __restrict__ in,
        ushort* __restrict__ out, int R, int C) {
    __shared__ float tile[32][33];
    int c0 = blockIdx.x * 32, r0 = blockIdx.y * 32;
    int tx = threadIdx.x, ty = threadIdx.y;
    for (int j = 0; j < 32; j += 8)
        tile[ty + j][tx] = in[(size_t)(r0 + ty + j) * C + c0 + tx];
    __syncthreads();
    for (int j = 0; j < 32; j += 8)
        out[(size_t)(c0 + ty + j) * R + r0 + tx] = f2bf(tile[tx][ty + j]);
}

// --------------------------------------------------------------- MFMA GEMM
#define GBM 128
#define GBN 128
#define GBK 32
__global__ __launch_bounds__(256) void gemm_bt_kernel(const ushort* __restrict__ A,
        const ushort* __restrict__ Bt, void* __restrict__ Cv, int M, int N, int K,
        const float* __restrict__ bias, const float* __restrict__ resid,
        int act, int out_f32) {
    __shared__ __align__(16) ushort As[GBM * GBK];
    __shared__ __align__(16) ushort Bs[GBN * GBK];
    int tid = threadIdx.x;
    int bm = blockIdx.y * GBM, bn = blockIdx.x * GBN;
    int wave = tid >> 6, lane = tid & 63;
    int wy = wave >> 1, wx = wave & 1;
    int quad = lane >> 4, l16 = lane & 15;
    int sr = tid >> 2;              // staging row 0..63
    int sc = (tid & 3) * 8;         // staging k offset (8 bf16 = 16B)
    const ushort* Ag = A + (size_t)(bm + sr) * K + sc;
    const ushort* Bg = Bt + (size_t)(bn + sr) * K + sc;

    floatx4 acc[4][4];
#pragma unroll
    for (int i = 0; i < 4; ++i)
#pragma unroll
        for (int j = 0; j < 4; ++j) { acc[i][j][0] = 0.f; acc[i][j][1] = 0.f; acc[i][j][2] = 0.f; acc[i][j][3] = 0.f; }

    for (int k0 = 0; k0 < K; k0 += GBK) {
        uint4 a0 = *(const uint4*)(Ag + k0);
        uint4 a1 = *(const uint4*)(Ag + (size_t)64 * K + k0);
        uint4 b0 = *(const uint4*)(Bg + k0);
        uint4 b1 = *(const uint4*)(Bg + (size_t)64 * K + k0);
        __syncthreads();
        *(uint4*)&As[sr * GBK + sc] = a0;
        *(uint4*)&As[(sr + 64) * GBK + sc] = a1;
        *(uint4*)&Bs[sr * GBK + sc] = b0;
        *(uint4*)&Bs[(sr + 64) * GBK + sc] = b1;
        __syncthreads();
        short8 af[4], bfv[4];
#pragma unroll
        for (int i = 0; i < 4; ++i)
            af[i] = *(const short8*)&As[(wy * 64 + i * 16 + l16) * GBK + quad * 8];
#pragma unroll
        for (int j = 0; j < 4; ++j)
            bfv[j] = *(const short8*)&Bs[(wx * 64 + j * 16 + l16) * GBK + quad * 8];
#pragma unroll
        for (int i = 0; i < 4; ++i)
#pragma unroll
            for (int j = 0; j < 4; ++j)
                acc[i][j] = __builtin_amdgcn_mfma_f32_16x16x32_bf16(af[i], bfv[j], acc[i][j], 0, 0, 0);
    }

#pragma unroll
    for (int i = 0; i < 4; ++i) {
        int row0 = bm + wy * 64 + i * 16 + quad * 4;
#pragma unroll
        for (int j = 0; j < 4; ++j) {
            int col = bn + wx * 64 + j * 16 + l16;
            float bv = bias ? bias[col] : 0.0f;
#pragma unroll
            for (int r = 0; r < 4; ++r) {
                float v = acc[i][j][r] + bv;
                if (act == 1) v = 0.5f * v * (1.0f + erff(v * 0.70710678118f));  // exact GELU
                size_t o = (size_t)(row0 + r) * N + col;
                if (out_f32) {
                    float vv = v + (resid ? resid[o] : 0.0f);
                    ((float*)Cv)[o] = vv;
                } else {
                    ((ushort*)Cv)[o] = f2bf(v);
                }
            }
        }
    }
}

// ---------------------------------------------------------------- launcher
extern "C" void kernel_launch(void* const* d_in, const int* in_sizes, int n_in,
                              void* d_out, int out_size, void* d_ws, size_t ws_size,
                              hipStream_t stream) {
    const float* x    = (const float*)d_in[0];
    const float* n1g  = (const float*)d_in[1];
    const float* n1b  = (const float*)d_in[2];
    const float* w1   = (const float*)d_in[3];
    const float* w2   = (const float*)d_in[4];
    const float* b1   = (const float*)d_in[5];
    const float* b2   = (const float*)d_in[6];
    const float* n2g  = (const float*)d_in[7];
    const float* n2b  = (const float*)d_in[8];
    const float* fc1w = (const float*)d_in[9];
    const float* fc1b = (const float*)d_in[10];
    const float* fc2w = (const float*)d_in[11];
    const float* fc2b = (const float*)d_in[12];
    float*  outf = (float*)d_out;
    ushort* outu = (ushort*)d_out;   // d_out (201 MB fp32) doubles as bf16 scratch

    // ws layout (bf16 elements), total ~161 MB:
    ushort* ws  = (ushort*)d_ws;
    ushort* W1t = ws;                               // [3072][768]
    ushort* W2t = W1t + (size_t)3072 * 768;         // [768][3072]
    ushort* Fr  = W2t + (size_t)768 * 3072;         // [256][129][768]
    ushort* Fi  = Fr + (size_t)NPLANE * SFREQ;
    ushort* hid = Fi + (size_t)NPLANE * SFREQ;      // [8192][3072]
    ushort* Abf = Fr;                               // alias: LN2 out (Fr/Fi dead by then)
    // d_out-resident bf16 scratch:
    ushort* S1  = outu;                             // LN1 out [65536][768]
    ushort* Gr  = outu;                             // [256][129][768] (S1 dead)
    ushort* Gi  = outu + (size_t)NPLANE * SFREQ;
    // d_out spare region (beyond Gr+Gi = 101.5 MB of 201 MB): mix weights bf16
    ushort* W1mix = outu + 2 * (size_t)NPLANE * SFREQ;   // [2][8][96][96]
    ushort* W2mix = W1mix + (size_t)2 * 8 * 96 * 96;

    // weight preprocessing
    transpose_kernel<<<dim3(3072 / 32, 768 / 32), dim3(32, 8), 0, stream>>>(fc1w, W1t, 768, 3072);
    transpose_kernel<<<dim3(768 / 32, 3072 / 32), dim3(32, 8), 0, stream>>>(fc2w, W2t, 3072, 768);
    wmix_prep_kernel<<<16, 256, 0, stream>>>(w1, W1mix);
    wmix_prep_kernel<<<16, 256, 0, stream>>>(w2, W2mix);

    // LN1: x (fp32) -> S1 (bf16, in d_out storage)
    ln_kernel<<<65536, 256, 0, stream>>>(x, n1g, n1b, S1);

    // rfft2 (ortho)
    dft_w_fwd_kernel<<<dim3(3, 33, NPLANE), 256, 0, stream>>>(S1, Fr, Fi);
    dft_h_kernel<<<dim3(SFREQ / 256, 32, 2), 256, 0, stream>>>(Fr, Fi, Gr, Gi, -1.0f);

    // block-diagonal complex MLP in frequency domain (MFMA)
    mix_mfma_kernel<<<dim3(NPOS / 128, 8), 256, 0, stream>>>(Gr, Gi, W1mix, b1, Fr, Fi, 0);
    mix_mfma_kernel<<<dim3(NPOS / 128, 8), 256, 0, stream>>>(Fr, Fi, W2mix, b2, Gr, Gi, 1);

    // irfft2 (ortho): inverse H, then inverse real W -> d_out fp32 spatial
    dft_h_kernel<<<dim3(SFREQ / 256, 32, 2), 256, 0, stream>>>(Gr, Gi, Fr, Fi, 1.0f);
    dft_w_inv_kernel<<<dim3(3, 64, NPLANE), 256, 0, stream>>>(Fr, Fi, outf);

    // LN2: d_out fp32 spatial -> Abf bf16 (ws)
    ln_kernel<<<65536, 256, 0, stream>>>(outf, n2g, n2b, Abf);

    // MLP: gelu(h@fc1+b1) @ fc2 + b2 + residual -> d_out fp32
    const int CH = 8192;
    for (int c = 0; c < 8; ++c) {
        const ushort* Aln = Abf + (size_t)c * CH * 768;
        gemm_bt_kernel<<<dim3(3072 / GBN, CH / GBM), 256, 0, stream>>>(
            Aln, W1t, hid, CH, 3072, 768, fc1b, nullptr, 1, 0);
        gemm_bt_kernel<<<dim3(768 / GBN, CH / GBM), 256, 0, stream>>>(
            hid, W2t, outf + (size_t)c * CH * 768, CH, 768, 3072, fc2b,
            x + (size_t)c * CH * 768, 0, 1);
    }
}

// Round 2
// 3139.723 us; speedup vs baseline: 2.4340x; 1.7891x over previous
//
#include <hip/hip_runtime.h>
#include <math.h>

#define Hh 128
#define Ww 256
#define Dd 768
#define NPLANE 256            // B*H
#define WF 129                // W/2+1
#define SFREQ (WF*Dd)         // 99072
#define NPOS (2*Hh*WF)        // 33024
#define LAMBDA_SS 0.01f

typedef short short8 __attribute__((ext_vector_type(8)));
typedef float floatx4 __attribute__((ext_vector_type(4)));

__device__ __forceinline__ float bf2f(ushort u) {
    union { unsigned int i; float f; } v; v.i = ((unsigned int)u) << 16; return v.f;
}
__device__ __forceinline__ ushort f2bf(float f) {
    union { float f; unsigned int i; } v; v.f = f;
    unsigned int r = v.i + 0x7fffu + ((v.i >> 16) & 1u);   // RTNE
    return (ushort)(r >> 16);
}

// ------------------------------------------------- LayerNorm: fp32 in, bf16 out
__global__ __launch_bounds__(256) void ln_kernel(const float* __restrict__ x,
        const float* __restrict__ g, const float* __restrict__ b,
        ushort* __restrict__ out) {
    int row = blockIdx.x;
    int tid = threadIdx.x;
    const float* xr = x + (size_t)row * Dd;
    float v0 = xr[tid], v1 = xr[tid + 256], v2 = xr[tid + 512];
    __shared__ float red[256];
    red[tid] = v0 + v1 + v2;
    __syncthreads();
    for (int o = 128; o > 0; o >>= 1) { if (tid < o) red[tid] += red[tid + o]; __syncthreads(); }
    float mean = red[0] * (1.0f / 768.0f);
    __syncthreads();
    float d0 = v0 - mean, d1 = v1 - mean, d2 = v2 - mean;
    red[tid] = d0 * d0 + d1 * d1 + d2 * d2;
    __syncthreads();
    for (int o = 128; o > 0; o >>= 1) { if (tid < o) red[tid] += red[tid + o]; __syncthreads(); }
    float inv = rsqrtf(red[0] * (1.0f / 768.0f) + 1e-5f);
    ushort* orow = out + (size_t)row * Dd;
    orow[tid]       = f2bf(d0 * inv * g[tid]       + b[tid]);
    orow[tid + 256] = f2bf(d1 * inv * g[tid + 256] + b[tid + 256]);
    orow[tid + 512] = f2bf(d2 * inv * g[tid + 512] + b[tid + 512]);
}

// ---------------------------------------------------- twiddle tables (bf16 hi+lo)
// layout inside tw (shorts):
#define TW_WFC_H  0         // [256][256] W-fwd cos/16 (rows wf<129, rest 0)
#define TW_WFC_L  65536
#define TW_WFS_H  131072    // [256][256] W-fwd -sin/16
#define TW_WFS_L  196608
#define TW_HC_H   262144    // [128][128] cos * 1/sqrt(128)
#define TW_HC_L   278528
#define TW_HS_H   294912    // +sin * sc
#define TW_HS_L   311296
#define TW_HSN_H  327680    // -sin * sc
#define TW_HSN_L  344064
#define TW_WIC_H  360448    // [256][160] wt*cos*0.125 (cols wf<129, rest 0)
#define TW_WIC_L  401408
#define TW_WISN_H 442368    // -wt*sin*0.125
#define TW_WISN_L 483328
#define TW_TOTAL  524288

__device__ __forceinline__ void split_bf(float v, ushort* hi, ushort* lo) {
    ushort h = f2bf(v);
    *hi = h;
    *lo = f2bf(v - bf2f(h));
}

__global__ __launch_bounds__(256) void twiddle_prep_kernel(ushort* __restrict__ tw) {
    int fam = blockIdx.y;
    int idx = blockIdx.x * 256 + threadIdx.x;
    if (fam == 0) {                       // W-fwd: [wf][w] 256x256
        if (idx >= 65536) return;
        int wf = idx >> 8, w = idx & 255;
        float c = 0.0f, s = 0.0f;
        if (wf < WF) {
            int t = (w * wf) & 255;
            float ang = (float)t * (float)(2.0 * M_PI / 256.0);
            c = cosf(ang) * 0.0625f;
            s = -sinf(ang) * 0.0625f;
        }
        split_bf(c, &tw[TW_WFC_H + idx], &tw[TW_WFC_L + idx]);
        split_bf(s, &tw[TW_WFS_H + idx], &tw[TW_WFS_L + idx]);
    } else if (fam == 1) {                // H: [a][b] 128x128 (symmetric: fwd & inv)
        if (idx >= 16384) return;
        int a = idx >> 7, b = idx & 127;
        int t = (a * b) & 127;
        float ang = (float)t * (float)(2.0 * M_PI / 128.0);
        const float sc = 0.08838834764831845f;   // 1/sqrt(128)
        float c = cosf(ang) * sc, s = sinf(ang) * sc;
        split_bf(c,  &tw[TW_HC_H + idx],  &tw[TW_HC_L + idx]);
        split_bf(s,  &tw[TW_HS_H + idx],  &tw[TW_HS_L + idx]);
        split_bf(-s, &tw[TW_HSN_H + idx], &tw[TW_HSN_L + idx]);
    } else {                              // W-inv: [w][wf] 256x160
        if (idx >= 40960) return;
        int w = idx / 160, wf = idx - w * 160;
        float c = 0.0f, s = 0.0f;
        if (wf < WF) {
            int t = (w * wf) & 255;
            float ang = (float)t * (float)(2.0 * M_PI / 256.0);
            float wt = (wf == 0 || wf == 128) ? 0.5f : 1.0f;
            c = wt * cosf(ang) * 0.125f;
            s = -wt * sinf(ang) * 0.125f;
        }
        split_bf(c, &tw[TW_WIC_H + idx],  &tw[TW_WIC_L + idx]);
        split_bf(s, &tw[TW_WISN_H + idx], &tw[TW_WISN_L + idx]);
    }
}

// ------------------------- batched bf16 transpose: in[z][R][C] -> out[z][C][Rpad]
// rows R..Rpad-1 of the K axis are zero-filled (GEMM K-padding).
__global__ __launch_bounds__(256) void transpose_bf_kernel(const ushort* __restrict__ in,
        ushort* __restrict__ out, int R, int C, int Rpad, size_t inB, size_t outB) {
    __shared__ ushort tile[32][33];
    int z = blockIdx.z;
    int c0 = blockIdx.x * 32, r0 = blockIdx.y * 32;
    int tx = threadIdx.x, ty = threadIdx.y;
    const ushort* ip = in + (size_t)z * inB;
    ushort* op = out + (size_t)z * outB;
    for (int j = 0; j < 32; j += 8) {
        int r = r0 + ty + j;
        tile[ty + j][tx] = (r < R) ? ip[(size_t)r * C + c0 + tx] : (ushort)0;
    }
    __syncthreads();
    for (int j = 0; j < 32; j += 8)
        op[(size_t)(c0 + ty + j) * Rpad + r0 + tx] = tile[tx][ty + j];
}

// ------------------------------------------------------------- DFT GEMM (MFMA)
// C[z][M][N] = (A1h+A1l)[M][K] @ B1[z][N][K]^T  (+ (A2h+A2l) @ B2^T if A2h)
// A = twiddle (bf16 hi/lo, scale folded in), B = transposed data, fp32 accum.
__global__ __launch_bounds__(256) void dftg_kernel(
        const ushort* __restrict__ A1h, const ushort* __restrict__ A1l,
        const ushort* __restrict__ A2h, const ushort* __restrict__ A2l,
        const ushort* __restrict__ B1, const ushort* __restrict__ B2,
        void* __restrict__ Cv, int M, int N, int K,
        size_t strideB, size_t strideC, int out_f32) {
    __shared__ __align__(16) ushort Bs1[128 * 40];   // +8 pad: conflict-free b128 reads
    __shared__ __align__(16) ushort Bs2[128 * 40];
    int tid = threadIdx.x;
    int bn = blockIdx.x * 128, bm = blockIdx.y * 128;
    int z = blockIdx.z;
    const ushort* b1g = B1 + (size_t)z * strideB;
    const ushort* b2g = B2 + (size_t)z * strideB;
    int wave = tid >> 6, lane = tid & 63;
    int wy = wave >> 1, wx = wave & 1;
    int quad = lane >> 4, l16 = lane & 15;
    int sr = tid >> 2, sc = (tid & 3) * 8;
    int P2 = (A2h != nullptr);

    size_t arow = (size_t)(bm + wy * 64 + l16) * K + quad * 8;
    const ushort* a1h_p = A1h + arow;
    const ushort* a1l_p = A1l + arow;
    const ushort* a2h_p = (P2 ? A2h : A1h) + arow;
    const ushort* a2l_p = (P2 ? A2l : A1l) + arow;

    floatx4 acc[4][4];
#pragma unroll
    for (int i = 0; i < 4; ++i)
#pragma unroll
        for (int j = 0; j < 4; ++j) { acc[i][j][0] = 0.f; acc[i][j][1] = 0.f; acc[i][j][2] = 0.f; acc[i][j][3] = 0.f; }

    for (int k0 = 0; k0 < K; k0 += 32) {
        uint4 b1a = *(const uint4*)(b1g + (size_t)(bn + sr) * K + k0 + sc);
        uint4 b1b = *(const uint4*)(b1g + (size_t)(bn + sr + 64) * K + k0 + sc);
        uint4 b2a, b2b;
        if (P2) {
            b2a = *(const uint4*)(b2g + (size_t)(bn + sr) * K + k0 + sc);
            b2b = *(const uint4*)(b2g + (size_t)(bn + sr + 64) * K + k0 + sc);
        }
        __syncthreads();
        *(uint4*)&Bs1[sr * 40 + sc] = b1a;
        *(uint4*)&Bs1[(sr + 64) * 40 + sc] = b1b;
        if (P2) {
            *(uint4*)&Bs2[sr * 40 + sc] = b2a;
            *(uint4*)&Bs2[(sr + 64) * 40 + sc] = b2b;
        }
        __syncthreads();
        short8 bf1[4], bf2[4];
#pragma unroll
        for (int j = 0; j < 4; ++j)
            bf1[j] = *(const short8*)&Bs1[(wx * 64 + j * 16 + l16) * 40 + quad * 8];
        if (P2) {
#pragma unroll
            for (int j = 0; j < 4; ++j)
                bf2[j] = *(const short8*)&Bs2[(wx * 64 + j * 16 + l16) * 40 + quad * 8];
        }
#pragma unroll
        for (int i = 0; i < 4; ++i) {
            size_t ao = (size_t)i * 16 * K + k0;
            short8 a1h_ = *(const short8*)(a1h_p + ao);
            short8 a1l_ = *(const short8*)(a1l_p + ao);
#pragma unroll
            for (int j = 0; j < 4; ++j) {
                acc[i][j] = __builtin_amdgcn_mfma_f32_16x16x32_bf16(a1h_, bf1[j], acc[i][j], 0, 0, 0);
                acc[i][j] = __builtin_amdgcn_mfma_f32_16x16x32_bf16(a1l_, bf1[j], acc[i][j], 0, 0, 0);
            }
            if (P2) {
                short8 a2h_ = *(const short8*)(a2h_p + ao);
                short8 a2l_ = *(const short8*)(a2l_p + ao);
#pragma unroll
                for (int j = 0; j < 4; ++j) {
                    acc[i][j] = __builtin_amdgcn_mfma_f32_16x16x32_bf16(a2h_, bf2[j], acc[i][j], 0, 0, 0);
                    acc[i][j] = __builtin_amdgcn_mfma_f32_16x16x32_bf16(a2l_, bf2[j], acc[i][j], 0, 0, 0);
                }
            }
        }
    }

#pragma unroll
    for (int i = 0; i < 4; ++i) {
        int row0 = bm + wy * 64 + i * 16 + quad * 4;
#pragma unroll
        for (int j = 0; j < 4; ++j) {
            int col = bn + wx * 64 + j * 16 + l16;
#pragma unroll
            for (int r = 0; r < 4; ++r) {
                int row = row0 + r;
                if (row < M) {
                    size_t o = (size_t)z * strideC + (size_t)row * N + col;
                    if (out_f32) ((float*)Cv)[o] = acc[i][j][r];
                    else         ((ushort*)Cv)[o] = f2bf(acc[i][j][r]);
                }
            }
        }
    }
}

// ------------------------------------------ mix weight prep: fp32 [ri][l][m][n]
// -> bf16 Bt layout [ri][l][n][m]
__global__ __launch_bounds__(256) void wmix_prep_kernel(const float* __restrict__ w,
        ushort* __restrict__ wt) {
    int mat = blockIdx.x;              // 0..15 = ri*8 + l
    const float* src = w + (size_t)mat * 96 * 96;
    ushort* dst = wt + (size_t)mat * 96 * 96;
    for (int idx = threadIdx.x; idx < 96 * 96; idx += 256) {
        int n = idx / 96, m = idx - n * 96;
        dst[idx] = f2bf(src[(size_t)m * 96 + n]);
    }
}

__device__ __forceinline__ short8 neg8(short8 a) {        // flip bf16 sign bits
    union { short8 s; unsigned int u[4]; } v; v.s = a;
    v.u[0] ^= 0x80008000u; v.u[1] ^= 0x80008000u;
    v.u[2] ^= 0x80008000u; v.u[3] ^= 0x80008000u;
    return v.s;
}

// ------------------------------------------------- block-diag channel mixing (MFMA)
#define WSTR 104
__global__ __launch_bounds__(256) void mix_mfma_kernel(const ushort* __restrict__ Xr,
        const ushort* __restrict__ Xi, const ushort* __restrict__ Wt,
        const float* __restrict__ bias, ushort* __restrict__ Or,
        ushort* __restrict__ Oi, int shrink) {
    int l = blockIdx.y;
    int bm = blockIdx.x * 128;
    int tid = threadIdx.x;
    int wv = tid >> 6, lane = tid & 63;
    int quad = lane >> 4, l16 = lane & 15;

    __shared__ __align__(16) ushort Wr_s[96 * WSTR];
    __shared__ __align__(16) ushort Wi_s[96 * WSTR];
    const ushort* wr_g = Wt + (size_t)l * 96 * 96;
    const ushort* wi_g = Wt + (size_t)(8 + l) * 96 * 96;
    for (int idx = tid; idx < (96 * 96) / 4; idx += 256) {
        int n = idx / 24, mq = idx - n * 24;
        *(uint2*)&Wr_s[n * WSTR + mq * 4] = *(const uint2*)(wr_g + (size_t)n * 96 + mq * 4);
        *(uint2*)&Wi_s[n * WSTR + mq * 4] = *(const uint2*)(wi_g + (size_t)n * 96 + mq * 4);
    }

    floatx4 accr[2][6], acci[2][6];
#pragma unroll
    for (int i = 0; i < 2; ++i)
#pragma unroll
        for (int j = 0; j < 6; ++j) {
            accr[i][j][0] = 0.f; accr[i][j][1] = 0.f; accr[i][j][2] = 0.f; accr[i][j][3] = 0.f;
            acci[i][j][0] = 0.f; acci[i][j][1] = 0.f; acci[i][j][2] = 0.f; acci[i][j][3] = 0.f;
        }

    int row = bm + wv * 32 + l16;
    const ushort* agr = Xr + (size_t)row * 768 + l * 96;
    const ushort* agi = Xi + (size_t)row * 768 + l * 96;
    __syncthreads();

#pragma unroll
    for (int ks = 0; ks < 3; ++ks) {
        int ko = ks * 32 + quad * 8;
        short8 ar0 = *(const short8*)(agr + ko);
        short8 ar1 = *(const short8*)(agr + (size_t)16 * 768 + ko);
        short8 ai0 = *(const short8*)(agi + ko);
        short8 ai1 = *(const short8*)(agi + (size_t)16 * 768 + ko);
        short8 an0 = neg8(ai0), an1 = neg8(ai1);
#pragma unroll
        for (int j = 0; j < 6; ++j) {
            short8 br = *(const short8*)&Wr_s[(j * 16 + l16) * WSTR + ko];
            short8 bi = *(const short8*)&Wi_s[(j * 16 + l16) * WSTR + ko];
            accr[0][j] = __builtin_amdgcn_mfma_f32_16x16x32_bf16(ar0, br, accr[0][j], 0, 0, 0);
            accr[0][j] = __builtin_amdgcn_mfma_f32_16x16x32_bf16(an0, bi, accr[0][j], 0, 0, 0);
            acci[0][j] = __builtin_amdgcn_mfma_f32_16x16x32_bf16(ar0, bi, acci[0][j], 0, 0, 0);
            acci[0][j] = __builtin_amdgcn_mfma_f32_16x16x32_bf16(ai0, br, acci[0][j], 0, 0, 0);
            accr[1][j] = __builtin_amdgcn_mfma_f32_16x16x32_bf16(ar1, br, accr[1][j], 0, 0, 0);
            accr[1][j] = __builtin_amdgcn_mfma_f32_16x16x32_bf16(an1, bi, accr[1][j], 0, 0, 0);
            acci[1][j] = __builtin_amdgcn_mfma_f32_16x16x32_bf16(ar1, bi, acci[1][j], 0, 0, 0);
            acci[1][j] = __builtin_amdgcn_mfma_f32_16x16x32_bf16(ai1, br, acci[1][j], 0, 0, 0);
        }
    }

#pragma unroll
    for (int i = 0; i < 2; ++i) {
        int row0 = bm + wv * 32 + i * 16 + quad * 4;
#pragma unroll
        for (int j = 0; j < 6; ++j) {
            int col = j * 16 + l16;
            float bvr = bias[l * 96 + col];
            float bvi = bias[768 + l * 96 + col];
#pragma unroll
            for (int r = 0; r < 4; ++r) {
                float vr = accr[i][j][r] + bvr;
                float vi = acci[i][j][r] + bvi;
                if (shrink) { vr = fmaxf(vr - LAMBDA_SS, 0.0f); vi = fmaxf(vi - LAMBDA_SS, 0.0f); }
                else        { vr = fmaxf(vr, 0.0f);             vi = fmaxf(vi, 0.0f); }
                size_t o = (size_t)(row0 + r) * 768 + l * 96 + col;
                Or[o] = f2bf(vr);
                Oi[o] = f2bf(vi);
            }
        }
    }
}

// ------------------------------------- fp32 -> bf16 transpose [R][C] -> [C][R]
__global__ __launch_bounds__(256) void transpose_kernel(const float* __restrict__ in,
        ushort* __restrict__ out, int R, int C) {
    __shared__ float tile[32][33];
    int c0 = blockIdx.x * 32, r0 = blockIdx.y * 32;
    int tx = threadIdx.x, ty = threadIdx.y;
    for (int j = 0; j < 32; j += 8)
        tile[ty + j][tx] = in[(size_t)(r0 + ty + j) * C + c0 + tx];
    __syncthreads();
    for (int j = 0; j < 32; j += 8)
        out[(size_t)(c0 + ty + j) * R + r0 + tx] = f2bf(tile[tx][ty + j]);
}

// --------------------------------------------------------------- MFMA GEMM (MLP)
#define GBM 128
#define GBN 128
#define GBK 32
__global__ __launch_bounds__(256) void gemm_bt_kernel(const ushort* __restrict__ A,
        const ushort* __restrict__ Bt, void* __restrict__ Cv, int M, int N, int K,
        const float* __restrict__ bias, const float* __restrict__ resid,
        int act, int out_f32) {
    __shared__ __align__(16) ushort As[GBM * GBK];
    __shared__ __align__(16) ushort Bs[GBN * GBK];
    int tid = threadIdx.x;
    int bm = blockIdx.y * GBM, bn = blockIdx.x * GBN;
    int wave = tid >> 6, lane = tid & 63;
    int wy = wave >> 1, wx = wave & 1;
    int quad = lane >> 4, l16 = lane & 15;
    int sr = tid >> 2;
    int sc = (tid & 3) * 8;
    const ushort* Ag = A + (size_t)(bm + sr) * K + sc;
    const ushort* Bg = Bt + (size_t)(bn + sr) * K + sc;

    floatx4 acc[4][4];
#pragma unroll
    for (int i = 0; i < 4; ++i)
#pragma unroll
        for (int j = 0; j < 4; ++j) { acc[i][j][0] = 0.f; acc[i][j][1] = 0.f; acc[i][j][2] = 0.f; acc[i][j][3] = 0.f; }

    for (int k0 = 0; k0 < K; k0 += GBK) {
        uint4 a0 = *(const uint4*)(Ag + k0);
        uint4 a1 = *(const uint4*)(Ag + (size_t)64 * K + k0);
        uint4 b0 = *(const uint4*)(Bg + k0);
        uint4 b1 = *(const uint4*)(Bg + (size_t)64 * K + k0);
        __syncthreads();
        *(uint4*)&As[sr * GBK + sc] = a0;
        *(uint4*)&As[(sr + 64) * GBK + sc] = a1;
        *(uint4*)&Bs[sr * GBK + sc] = b0;
        *(uint4*)&Bs[(sr + 64) * GBK + sc] = b1;
        __syncthreads();
        short8 af[4], bfv[4];
#pragma unroll
        for (int i = 0; i < 4; ++i)
            af[i] = *(const short8*)&As[(wy * 64 + i * 16 + l16) * GBK + quad * 8];
#pragma unroll
        for (int j = 0; j < 4; ++j)
            bfv[j] = *(const short8*)&Bs[(wx * 64 + j * 16 + l16) * GBK + quad * 8];
#pragma unroll
        for (int i = 0; i < 4; ++i)
#pragma unroll
            for (int j = 0; j < 4; ++j)
                acc[i][j] = __builtin_amdgcn_mfma_f32_16x16x32_bf16(af[i], bfv[j], acc[i][j], 0, 0, 0);
    }

#pragma unroll
    for (int i = 0; i < 4; ++i) {
        int row0 = bm + wy * 64 + i * 16 + quad * 4;
#pragma unroll
        for (int j = 0; j < 4; ++j) {
            int col = bn + wx * 64 + j * 16 + l16;
            float bv = bias ? bias[col] : 0.0f;
#pragma unroll
            for (int r = 0; r < 4; ++r) {
                float v = acc[i][j][r] + bv;
                if (act == 1) v = 0.5f * v * (1.0f + erff(v * 0.70710678118f));  // exact GELU
                size_t o = (size_t)(row0 + r) * N + col;
                if (out_f32) {
                    float vv = v + (resid ? resid[o] : 0.0f);
                    ((float*)Cv)[o] = vv;
                } else {
                    ((ushort*)Cv)[o] = f2bf(v);
                }
            }
        }
    }
}

// ---------------------------------------------------------------- launcher
extern "C" void kernel_launch(void* const* d_in, const int* in_sizes, int n_in,
                              void* d_out, int out_size, void* d_ws, size_t ws_size,
                              hipStream_t stream) {
    const float* x    = (const float*)d_in[0];
    const float* n1g  = (const float*)d_in[1];
    const float* n1b  = (const float*)d_in[2];
    const float* w1   = (const float*)d_in[3];
    const float* w2   = (const float*)d_in[4];
    const float* b1   = (const float*)d_in[5];
    const float* b2   = (const float*)d_in[6];
    const float* n2g  = (const float*)d_in[7];
    const float* n2b  = (const float*)d_in[8];
    const float* fc1w = (const float*)d_in[9];
    const float* fc1b = (const float*)d_in[10];
    const float* fc2w = (const float*)d_in[11];
    const float* fc2b = (const float*)d_in[12];
    float*  outf = (float*)d_out;
    ushort* outu = (ushort*)d_out;   // d_out (201 MB) doubles as bf16 scratch

    // ---- ws fixed region (shorts)
    ushort* ws  = (ushort*)d_ws;
    ushort* W1t = ws;                               // [3072][768]     2,359,296
    ushort* W2t = W1t + (size_t)3072 * 768;         // [768][3072]     2,359,296
    ushort* tw  = W2t + (size_t)768 * 3072;         // twiddles          524,288
    ushort* AR  = tw + TW_TOTAL;                    // arena (75,497,472 shorts)

    const size_t FSZ = (size_t)NPLANE * SFREQ;      // 25,362,432 (bf16 freq array)
    // arena aliases (time-disjoint):
    ushort* S1t = AR;                               // [256][768][256]  50,331,648
    ushort* FrT = AR;                               // [2][99072][128]  12,681,216 ea
    ushort* FiT = AR + FSZ;
    ushort* Mr  = AR;                               // mix1 out [NPOS][768]
    ushort* Mi  = AR + FSZ;
    ushort* NrT = AR;                               // [2][99072][128]
    ushort* NiT = AR + FSZ;
    ushort* HrT = AR;                               // [256][768][160]  31,457,280 ea
    ushort* HiT = AR + (size_t)256 * 768 * 160;
    ushort* Abf = AR;                               // LN2 out [65536][768]
    ushort* hid = AR + (size_t)65536 * 768;         // [8192][3072]  25,165,824

    // d_out aliases (time-disjoint):
    ushort* S1 = outu;                              // LN1 out [65536][768]
    ushort* Fr = outu;                              // [256][129][768]
    ushort* Fi = outu + FSZ;
    ushort* Gr = outu;                              // H-fwd out
    ushort* Gi = outu + FSZ;
    ushort* Nr = outu;                              // mix2 out
    ushort* Ni = outu + FSZ;
    ushort* Hr = outu;                              // H-inv out
    ushort* Hi = outu + FSZ;
    ushort* W1mix = outu + 2 * FSZ;                 // mix weights (above 2*FSZ)
    ushort* W2mix = W1mix + (size_t)2 * 8 * 96 * 96;

    // ---- weight / twiddle prep
    transpose_kernel<<<dim3(3072 / 32, 768 / 32), dim3(32, 8), 0, stream>>>(fc1w, W1t, 768, 3072);
    transpose_kernel<<<dim3(768 / 32, 3072 / 32), dim3(32, 8), 0, stream>>>(fc2w, W2t, 3072, 768);
    wmix_prep_kernel<<<16, 256, 0, stream>>>(w1, W1mix);
    wmix_prep_kernel<<<16, 256, 0, stream>>>(w2, W2mix);
    twiddle_prep_kernel<<<dim3(256, 3), 256, 0, stream>>>(tw);

    // ---- LN1: x -> S1 (bf16 in d_out)
    ln_kernel<<<65536, 256, 0, stream>>>(x, n1g, n1b, S1);

    // ---- W-fwd: transpose per plane, then GEMM  Fr = Cwf@S1t^T, Fi = Swf@S1t^T
    transpose_bf_kernel<<<dim3(768 / 32, 256 / 32, 256), dim3(32, 8), 0, stream>>>(
        S1, S1t, 256, 768, 256, (size_t)256 * 768, (size_t)768 * 256);
    dftg_kernel<<<dim3(768 / 128, 2, 256), 256, 0, stream>>>(
        tw + TW_WFC_H, tw + TW_WFC_L, nullptr, nullptr, S1t, S1t,
        Fr, WF, 768, 256, (size_t)768 * 256, (size_t)SFREQ, 0);
    dftg_kernel<<<dim3(768 / 128, 2, 256), 256, 0, stream>>>(
        tw + TW_WFS_H, tw + TW_WFS_L, nullptr, nullptr, S1t, S1t,
        Fi, WF, 768, 256, (size_t)768 * 256, (size_t)SFREQ, 0);

    // ---- H-fwd: transpose [b][128][99072] -> [b][99072][128], then complex GEMM
    transpose_bf_kernel<<<dim3(SFREQ / 32, 128 / 32, 2), dim3(32, 8), 0, stream>>>(
        Fr, FrT, 128, SFREQ, 128, (size_t)128 * SFREQ, (size_t)128 * SFREQ);
    transpose_bf_kernel<<<dim3(SFREQ / 32, 128 / 32, 2), dim3(32, 8), 0, stream>>>(
        Fi, FiT, 128, SFREQ, 128, (size_t)128 * SFREQ, (size_t)128 * SFREQ);
    dftg_kernel<<<dim3(SFREQ / 128, 1, 2), 256, 0, stream>>>(        // Gr = C@Xr + S@Xi
        tw + TW_HC_H, tw + TW_HC_L, tw + TW_HS_H, tw + TW_HS_L, FrT, FiT,
        Gr, 128, SFREQ, 128, (size_t)128 * SFREQ, (size_t)128 * SFREQ, 0);
    dftg_kernel<<<dim3(SFREQ / 128, 1, 2), 256, 0, stream>>>(        // Gi = C@Xi - S@Xr
        tw + TW_HC_H, tw + TW_HC_L, tw + TW_HSN_H, tw + TW_HSN_L, FiT, FrT,
        Gi, 128, SFREQ, 128, (size_t)128 * SFREQ, (size_t)128 * SFREQ, 0);

    // ---- block-diagonal complex MLP (MFMA)
    mix_mfma_kernel<<<dim3(NPOS / 128, 8), 256, 0, stream>>>(Gr, Gi, W1mix, b1, Mr, Mi, 0);
    mix_mfma_kernel<<<dim3(NPOS / 128, 8), 256, 0, stream>>>(Mr, Mi, W2mix, b2, Nr, Ni, 1);

    // ---- H-inv: transpose, then complex GEMM (conjugate twiddles)
    transpose_bf_kernel<<<dim3(SFREQ / 32, 128 / 32, 2), dim3(32, 8), 0, stream>>>(
        Nr, NrT, 128, SFREQ, 128, (size_t)128 * SFREQ, (size_t)128 * SFREQ);
    transpose_bf_kernel<<<dim3(SFREQ / 32, 128 / 32, 2), dim3(32, 8), 0, stream>>>(
        Ni, NiT, 128, SFREQ, 128, (size_t)128 * SFREQ, (size_t)128 * SFREQ);
    dftg_kernel<<<dim3(SFREQ / 128, 1, 2), 256, 0, stream>>>(        // Hr = C@Xr - S@Xi
        tw + TW_HC_H, tw + TW_HC_L, tw + TW_HSN_H, tw + TW_HSN_L, NrT, NiT,
        Hr, 128, SFREQ, 128, (size_t)128 * SFREQ, (size_t)128 * SFREQ, 0);
    dftg_kernel<<<dim3(SFREQ / 128, 1, 2), 256, 0, stream>>>(        // Hi = C@Xi + S@Xr
        tw + TW_HC_H, tw + TW_HC_L, tw + TW_HS_H, tw + TW_HS_L, NiT, NrT,
        Hi, 128, SFREQ, 128, (size_t)128 * SFREQ, (size_t)128 * SFREQ, 0);

    // ---- W-inv: transpose [p][129][768] -> [p][768][160] (K-pad), GEMM -> spatial fp32
    transpose_bf_kernel<<<dim3(768 / 32, 5, 256), dim3(32, 8), 0, stream>>>(
        Hr, HrT, WF, 768, 160, (size_t)SFREQ, (size_t)768 * 160);
    transpose_bf_kernel<<<dim3(768 / 32, 5, 256), dim3(32, 8), 0, stream>>>(
        Hi, HiT, WF, 768, 160, (size_t)SFREQ, (size_t)768 * 160);
    dftg_kernel<<<dim3(768 / 128, 2, 256), 256, 0, stream>>>(        // x = C'@Hr - S'@Hi
        tw + TW_WIC_H, tw + TW_WIC_L, tw + TW_WISN_H, tw + TW_WISN_L, HrT, HiT,
        outf, 256, 768, 160, (size_t)768 * 160, (size_t)256 * 768, 1);

    // ---- LN2: d_out fp32 spatial -> Abf bf16 (ws)
    ln_kernel<<<65536, 256, 0, stream>>>(outf, n2g, n2b, Abf);

    // ---- MLP: gelu(h@fc1+b1) @ fc2 + b2 + residual -> d_out fp32
    const int CH = 8192;
    for (int c = 0; c < 8; ++c) {
        const ushort* Aln = Abf + (size_t)c * CH * 768;
        gemm_bt_kernel<<<dim3(3072 / GBN, CH / GBM), 256, 0, stream>>>(
            Aln, W1t, hid, CH, 3072, 768, fc1b, nullptr, 1, 0);
        gemm_bt_kernel<<<dim3(768 / GBN, CH / GBM), 256, 0, stream>>>(
            hid, W2t, outf + (size_t)c * CH * 768, CH, 768, 3072, fc2b,
            x + (size_t)c * CH * 768, 0, 1);
    }
}

// Round 3
// 2991.472 us; speedup vs baseline: 2.5546x; 1.0496x over previous
//
#include <hip/hip_runtime.h>
#include <math.h>

#define Hh 128
#define Ww 256
#define Dd 768
#define NPLANE 256            // B*H
#define WF 129                // W/2+1
#define SFREQ (WF*Dd)         // 99072
#define NPOS (2*Hh*WF)        // 33024
#define LAMBDA_SS 0.01f

typedef short short8 __attribute__((ext_vector_type(8)));
typedef float floatx4 __attribute__((ext_vector_type(4)));

__device__ __forceinline__ float bf2f(ushort u) {
    union { unsigned int i; float f; } v; v.i = ((unsigned int)u) << 16; return v.f;
}
__device__ __forceinline__ ushort f2bf(float f) {
    union { float f; unsigned int i; } v; v.f = f;
    unsigned int r = v.i + 0x7fffu + ((v.i >> 16) & 1u);   // RTNE
    return (ushort)(r >> 16);
}
__device__ __forceinline__ short8 neg8(short8 a) {        // flip bf16 sign bits
    union { short8 s; unsigned int u[4]; } v; v.s = a;
    v.u[0] ^= 0x80008000u; v.u[1] ^= 0x80008000u;
    v.u[2] ^= 0x80008000u; v.u[3] ^= 0x80008000u;
    return v.s;
}

// ------------------------------------------------- LayerNorm: fp32 in, bf16 out
__global__ __launch_bounds__(256) void ln_kernel(const float* __restrict__ x,
        const float* __restrict__ g, const float* __restrict__ b,
        ushort* __restrict__ out) {
    int row = blockIdx.x;
    int tid = threadIdx.x;
    const float* xr = x + (size_t)row * Dd;
    float v0 = xr[tid], v1 = xr[tid + 256], v2 = xr[tid + 512];
    __shared__ float red[256];
    red[tid] = v0 + v1 + v2;
    __syncthreads();
    for (int o = 128; o > 0; o >>= 1) { if (tid < o) red[tid] += red[tid + o]; __syncthreads(); }
    float mean = red[0] * (1.0f / 768.0f);
    __syncthreads();
    float d0 = v0 - mean, d1 = v1 - mean, d2 = v2 - mean;
    red[tid] = d0 * d0 + d1 * d1 + d2 * d2;
    __syncthreads();
    for (int o = 128; o > 0; o >>= 1) { if (tid < o) red[tid] += red[tid + o]; __syncthreads(); }
    float inv = rsqrtf(red[0] * (1.0f / 768.0f) + 1e-5f);
    ushort* orow = out + (size_t)row * Dd;
    orow[tid]       = f2bf(d0 * inv * g[tid]       + b[tid]);
    orow[tid + 256] = f2bf(d1 * inv * g[tid + 256] + b[tid + 256]);
    orow[tid + 512] = f2bf(d2 * inv * g[tid + 512] + b[tid + 512]);
}

// ---------------------------------------------------- twiddle tables (bf16 hi+lo)
#define TW_WFC_H  0         // [256][256] W-fwd cos/16 (rows wf<129, rest 0)
#define TW_WFC_L  65536
#define TW_WFS_H  131072    // [256][256] W-fwd -sin/16
#define TW_WFS_L  196608
#define TW_HC_H   262144    // [128][128] cos * 1/sqrt(128)
#define TW_HC_L   278528
#define TW_HS_H   294912    // +sin * sc
#define TW_HS_L   311296
#define TW_HSN_H  327680    // -sin * sc (unused by new path; kept)
#define TW_HSN_L  344064
#define TW_WIC_H  360448    // [256][160] wt*cos*0.125 (cols wf<129, rest 0)
#define TW_WIC_L  401408
#define TW_WISN_H 442368    // -wt*sin*0.125
#define TW_WISN_L 483328
#define TW_TOTAL  524288

__device__ __forceinline__ void split_bf(float v, ushort* hi, ushort* lo) {
    ushort h = f2bf(v);
    *hi = h;
    *lo = f2bf(v - bf2f(h));
}

__global__ __launch_bounds__(256) void twiddle_prep_kernel(ushort* __restrict__ tw) {
    int fam = blockIdx.y;
    int idx = blockIdx.x * 256 + threadIdx.x;
    if (fam == 0) {                       // W-fwd: [wf][w] 256x256
        if (idx >= 65536) return;
        int wf = idx >> 8, w = idx & 255;
        float c = 0.0f, s = 0.0f;
        if (wf < WF) {
            int t = (w * wf) & 255;
            float ang = (float)t * (float)(2.0 * M_PI / 256.0);
            c = cosf(ang) * 0.0625f;
            s = -sinf(ang) * 0.0625f;
        }
        split_bf(c, &tw[TW_WFC_H + idx], &tw[TW_WFC_L + idx]);
        split_bf(s, &tw[TW_WFS_H + idx], &tw[TW_WFS_L + idx]);
    } else if (fam == 1) {                // H: [a][b] 128x128 (symmetric: fwd & inv)
        if (idx >= 16384) return;
        int a = idx >> 7, b = idx & 127;
        int t = (a * b) & 127;
        float ang = (float)t * (float)(2.0 * M_PI / 128.0);
        const float sc = 0.08838834764831845f;   // 1/sqrt(128)
        float c = cosf(ang) * sc, s = sinf(ang) * sc;
        split_bf(c,  &tw[TW_HC_H + idx],  &tw[TW_HC_L + idx]);
        split_bf(s,  &tw[TW_HS_H + idx],  &tw[TW_HS_L + idx]);
        split_bf(-s, &tw[TW_HSN_H + idx], &tw[TW_HSN_L + idx]);
    } else {                              // W-inv: [w][wf] 256x160
        if (idx >= 40960) return;
        int w = idx / 160, wf = idx - w * 160;
        float c = 0.0f, s = 0.0f;
        if (wf < WF) {
            int t = (w * wf) & 255;
            float ang = (float)t * (float)(2.0 * M_PI / 256.0);
            float wt = (wf == 0 || wf == 128) ? 0.5f : 1.0f;
            c = wt * cosf(ang) * 0.125f;
            s = -wt * sinf(ang) * 0.125f;
        }
        split_bf(c, &tw[TW_WIC_H + idx],  &tw[TW_WIC_L + idx]);
        split_bf(s, &tw[TW_WISN_H + idx], &tw[TW_WISN_L + idx]);
    }
}

// ------------------------- batched bf16 transpose: in[z][R][C] -> out[z][C][Rpad]
__global__ __launch_bounds__(256) void transpose_bf_kernel(const ushort* __restrict__ in,
        ushort* __restrict__ out, int R, int C, int Rpad, size_t inB, size_t outB) {
    __shared__ ushort tile[32][33];
    int z = blockIdx.z;
    int c0 = blockIdx.x * 32, r0 = blockIdx.y * 32;
    int tx = threadIdx.x, ty = threadIdx.y;
    const ushort* ip = in + (size_t)z * inB;
    ushort* op = out + (size_t)z * outB;
    for (int j = 0; j < 32; j += 8) {
        int r = r0 + ty + j;
        tile[ty + j][tx] = (r < R) ? ip[(size_t)r * C + c0 + tx] : (ushort)0;
    }
    __syncthreads();
    for (int j = 0; j < 32; j += 8)
        op[(size_t)(c0 + ty + j) * Rpad + r0 + tx] = tile[tx][ty + j];
}

// ---------------------------------------------- dual-output complex DFT GEMM
// mode 0: O1 = A1@B1^T ; O2 = A2@B1^T        (A = bf16 hi+lo pairs, scale folded)
// mode 1: O1 = A1@B1 + A2@B2 ; O2 = A1@B2 - A2@B1
// Epilogue: LDS-staged, full-line coalesced bf16 stores.
#define CSTR 144   // Cs row stride (shorts): conflict-free staging
__global__ __launch_bounds__(256, 2) void dftc_kernel(
        const ushort* __restrict__ A1h, const ushort* __restrict__ A1l,
        const ushort* __restrict__ A2h, const ushort* __restrict__ A2l,
        const ushort* __restrict__ B1, const ushort* __restrict__ B2,
        ushort* __restrict__ O1, ushort* __restrict__ O2,
        int M, int N, int K, size_t strideB, size_t strideC, int mode) {
    __shared__ __align__(16) ushort smem[128 * CSTR];   // 36864 B
    ushort* Bs1 = smem;                                  // [128][40] during loop
    ushort* Bs2 = smem + 5120;
    int tid = threadIdx.x;
    int bn = blockIdx.x * 128, bm = blockIdx.y * 128;
    int z = blockIdx.z;
    const ushort* b1g = B1 + (size_t)z * strideB;
    const ushort* b2g = B2 + (size_t)z * strideB;
    int wave = tid >> 6, lane = tid & 63;
    int wy = wave >> 1, wx = wave & 1;
    int quad = lane >> 4, l16 = lane & 15;
    int sr = tid >> 2, sc = (tid & 3) * 8;

    size_t arow = (size_t)(bm + wy * 64 + l16) * K + quad * 8;
    const ushort* a1h_p = A1h + arow;
    const ushort* a1l_p = A1l + arow;
    const ushort* a2h_p = A2h + arow;
    const ushort* a2l_p = A2l + arow;

    floatx4 acc1[4][4], acc2[4][4];
#pragma unroll
    for (int i = 0; i < 4; ++i)
#pragma unroll
        for (int j = 0; j < 4; ++j) {
            acc1[i][j][0] = 0.f; acc1[i][j][1] = 0.f; acc1[i][j][2] = 0.f; acc1[i][j][3] = 0.f;
            acc2[i][j][0] = 0.f; acc2[i][j][1] = 0.f; acc2[i][j][2] = 0.f; acc2[i][j][3] = 0.f;
        }

    for (int k0 = 0; k0 < K; k0 += 32) {
        uint4 b1a = *(const uint4*)(b1g + (size_t)(bn + sr) * K + k0 + sc);
        uint4 b1b = *(const uint4*)(b1g + (size_t)(bn + sr + 64) * K + k0 + sc);
        uint4 b2a, b2b;
        if (mode) {
            b2a = *(const uint4*)(b2g + (size_t)(bn + sr) * K + k0 + sc);
            b2b = *(const uint4*)(b2g + (size_t)(bn + sr + 64) * K + k0 + sc);
        }
        __syncthreads();
        *(uint4*)&Bs1[sr * 40 + sc] = b1a;
        *(uint4*)&Bs1[(sr + 64) * 40 + sc] = b1b;
        if (mode) {
            *(uint4*)&Bs2[sr * 40 + sc] = b2a;
            *(uint4*)&Bs2[(sr + 64) * 40 + sc] = b2b;
        }
        __syncthreads();
        short8 bf1[4], bf2[4];
#pragma unroll
        for (int j = 0; j < 4; ++j)
            bf1[j] = *(const short8*)&Bs1[(wx * 64 + j * 16 + l16) * 40 + quad * 8];
        if (mode) {
#pragma unroll
            for (int j = 0; j < 4; ++j)
                bf2[j] = *(const short8*)&Bs2[(wx * 64 + j * 16 + l16) * 40 + quad * 8];
        }
#pragma unroll
        for (int i = 0; i < 4; ++i) {
            size_t ao = (size_t)i * 16 * K + k0;
            short8 a1h_ = *(const short8*)(a1h_p + ao);
            short8 a1l_ = *(const short8*)(a1l_p + ao);
            short8 a2h_ = *(const short8*)(a2h_p + ao);
            short8 a2l_ = *(const short8*)(a2l_p + ao);
            if (mode) {
#pragma unroll
                for (int j = 0; j < 4; ++j) {
                    acc1[i][j] = __builtin_amdgcn_mfma_f32_16x16x32_bf16(a1h_, bf1[j], acc1[i][j], 0, 0, 0);
                    acc1[i][j] = __builtin_amdgcn_mfma_f32_16x16x32_bf16(a1l_, bf1[j], acc1[i][j], 0, 0, 0);
                    acc1[i][j] = __builtin_amdgcn_mfma_f32_16x16x32_bf16(a2h_, bf2[j], acc1[i][j], 0, 0, 0);
                    acc1[i][j] = __builtin_amdgcn_mfma_f32_16x16x32_bf16(a2l_, bf2[j], acc1[i][j], 0, 0, 0);
                }
                short8 n2h = neg8(a2h_), n2l = neg8(a2l_);
#pragma unroll
                for (int j = 0; j < 4; ++j) {
                    acc2[i][j] = __builtin_amdgcn_mfma_f32_16x16x32_bf16(a1h_, bf2[j], acc2[i][j], 0, 0, 0);
                    acc2[i][j] = __builtin_amdgcn_mfma_f32_16x16x32_bf16(a1l_, bf2[j], acc2[i][j], 0, 0, 0);
                    acc2[i][j] = __builtin_amdgcn_mfma_f32_16x16x32_bf16(n2h, bf1[j], acc2[i][j], 0, 0, 0);
                    acc2[i][j] = __builtin_amdgcn_mfma_f32_16x16x32_bf16(n2l, bf1[j], acc2[i][j], 0, 0, 0);
                }
            } else {
#pragma unroll
                for (int j = 0; j < 4; ++j) {
                    acc1[i][j] = __builtin_amdgcn_mfma_f32_16x16x32_bf16(a1h_, bf1[j], acc1[i][j], 0, 0, 0);
                    acc1[i][j] = __builtin_amdgcn_mfma_f32_16x16x32_bf16(a1l_, bf1[j], acc1[i][j], 0, 0, 0);
                    acc2[i][j] = __builtin_amdgcn_mfma_f32_16x16x32_bf16(a2h_, bf1[j], acc2[i][j], 0, 0, 0);
                    acc2[i][j] = __builtin_amdgcn_mfma_f32_16x16x32_bf16(a2l_, bf1[j], acc2[i][j], 0, 0, 0);
                }
            }
        }
    }

    // ---- epilogue: stage each output tile in LDS, store full coalesced lines
    int srow = tid >> 4;               // 0..15
    int schunk = (tid & 15) * 8;       // col start (shorts)
#pragma unroll
    for (int half = 0; half < 2; ++half) {
        ushort* Optr = half ? O2 : O1;
        __syncthreads();
#pragma unroll
        for (int i = 0; i < 4; ++i) {
            int r0 = (wy * 64 + i * 16 + quad * 4) * CSTR;
#pragma unroll
            for (int j = 0; j < 4; ++j) {
                int cc = wx * 64 + j * 16 + l16;
#pragma unroll
                for (int r = 0; r < 4; ++r) {
                    float v = half ? acc2[i][j][r] : acc1[i][j][r];
                    smem[r0 + r * CSTR + cc] = f2bf(v);
                }
            }
        }
        __syncthreads();
#pragma unroll
        for (int p = 0; p < 8; ++p) {
            int row = p * 16 + srow;
            int grow = bm + row;
            if (grow < M) {
                uint4 v = *(const uint4*)&smem[row * CSTR + schunk];
                *(uint4*)&Optr[(size_t)z * strideC + (size_t)grow * N + bn + schunk] = v;
            }
        }
    }
}

// ---------------------------------------------- W-inverse DFT GEMM, fp32 out
// O = A1@B1 + A2@B2 (A = bf16 hi/lo pairs). LDS-staged coalesced fp32 stores.
__global__ __launch_bounds__(256, 2) void dftwi_kernel(
        const ushort* __restrict__ A1h, const ushort* __restrict__ A1l,
        const ushort* __restrict__ A2h, const ushort* __restrict__ A2l,
        const ushort* __restrict__ B1, const ushort* __restrict__ B2,
        float* __restrict__ O, int M, int N, int K, size_t strideB, size_t strideC) {
    __shared__ __align__(16) ushort smem[128 * CSTR];   // 36864 B
    ushort* Bs1 = smem;
    ushort* Bs2 = smem + 5120;
    float* Csf = (float*)smem;                           // [64][144] during epilogue
    int tid = threadIdx.x;
    int bn = blockIdx.x * 128, bm = blockIdx.y * 128;
    int z = blockIdx.z;
    const ushort* b1g = B1 + (size_t)z * strideB;
    const ushort* b2g = B2 + (size_t)z * strideB;
    int wave = tid >> 6, lane = tid & 63;
    int wy = wave >> 1, wx = wave & 1;
    int quad = lane >> 4, l16 = lane & 15;
    int sr = tid >> 2, sc = (tid & 3) * 8;

    size_t arow = (size_t)(bm + wy * 64 + l16) * K + quad * 8;
    const ushort* a1h_p = A1h + arow;
    const ushort* a1l_p = A1l + arow;
    const ushort* a2h_p = A2h + arow;
    const ushort* a2l_p = A2l + arow;

    floatx4 acc[4][4];
#pragma unroll
    for (int i = 0; i < 4; ++i)
#pragma unroll
        for (int j = 0; j < 4; ++j) { acc[i][j][0] = 0.f; acc[i][j][1] = 0.f; acc[i][j][2] = 0.f; acc[i][j][3] = 0.f; }

    for (int k0 = 0; k0 < K; k0 += 32) {
        uint4 b1a = *(const uint4*)(b1g + (size_t)(bn + sr) * K + k0 + sc);
        uint4 b1b = *(const uint4*)(b1g + (size_t)(bn + sr + 64) * K + k0 + sc);
        uint4 b2a = *(const uint4*)(b2g + (size_t)(bn + sr) * K + k0 + sc);
        uint4 b2b = *(const uint4*)(b2g + (size_t)(bn + sr + 64) * K + k0 + sc);
        __syncthreads();
        *(uint4*)&Bs1[sr * 40 + sc] = b1a;
        *(uint4*)&Bs1[(sr + 64) * 40 + sc] = b1b;
        *(uint4*)&Bs2[sr * 40 + sc] = b2a;
        *(uint4*)&Bs2[(sr + 64) * 40 + sc] = b2b;
        __syncthreads();
        short8 bf1[4], bf2[4];
#pragma unroll
        for (int j = 0; j < 4; ++j) {
            bf1[j] = *(const short8*)&Bs1[(wx * 64 + j * 16 + l16) * 40 + quad * 8];
            bf2[j] = *(const short8*)&Bs2[(wx * 64 + j * 16 + l16) * 40 + quad * 8];
        }
#pragma unroll
        for (int i = 0; i < 4; ++i) {
            size_t ao = (size_t)i * 16 * K + k0;
            short8 a1h_ = *(const short8*)(a1h_p + ao);
            short8 a1l_ = *(const short8*)(a1l_p + ao);
            short8 a2h_ = *(const short8*)(a2h_p + ao);
            short8 a2l_ = *(const short8*)(a2l_p + ao);
#pragma unroll
            for (int j = 0; j < 4; ++j) {
                acc[i][j] = __builtin_amdgcn_mfma_f32_16x16x32_bf16(a1h_, bf1[j], acc[i][j], 0, 0, 0);
                acc[i][j] = __builtin_amdgcn_mfma_f32_16x16x32_bf16(a1l_, bf1[j], acc[i][j], 0, 0, 0);
                acc[i][j] = __builtin_amdgcn_mfma_f32_16x16x32_bf16(a2h_, bf2[j], acc[i][j], 0, 0, 0);
                acc[i][j] = __builtin_amdgcn_mfma_f32_16x16x32_bf16(a2l_, bf2[j], acc[i][j], 0, 0, 0);
            }
        }
    }

    // ---- epilogue: two 64-row halves through LDS, full-line fp32 stores
    int srow = tid >> 5;               // 0..7
    int chunk = (tid & 31) * 4;        // float col
#pragma unroll
    for (int h = 0; h < 2; ++h) {
        __syncthreads();
        if (wy == h) {
#pragma unroll
            for (int i = 0; i < 4; ++i) {
                int r0 = (i * 16 + quad * 4) * CSTR;
#pragma unroll
                for (int j = 0; j < 4; ++j) {
                    int cc = wx * 64 + j * 16 + l16;
#pragma unroll
                    for (int r = 0; r < 4; ++r)
                        Csf[r0 + r * CSTR + cc] = acc[i][j][r];
                }
            }
        }
        __syncthreads();
#pragma unroll
        for (int p = 0; p < 8; ++p) {
            int row = p * 8 + srow;
            uint4 v = *(const uint4*)&Csf[row * CSTR + chunk];
            *(uint4*)&O[(size_t)z * strideC + (size_t)(bm + h * 64 + row) * N + bn + chunk] = v;
        }
    }
}

// ------------------------------------------ mix weight prep: fp32 [ri][l][m][n]
// -> bf16 Bt layout [ri][l][n][m]
__global__ __launch_bounds__(256) void wmix_prep_kernel(const float* __restrict__ w,
        ushort* __restrict__ wt) {
    int mat = blockIdx.x;              // 0..15 = ri*8 + l
    const float* src = w + (size_t)mat * 96 * 96;
    ushort* dst = wt + (size_t)mat * 96 * 96;
    for (int idx = threadIdx.x; idx < 96 * 96; idx += 256) {
        int n = idx / 96, m = idx - n * 96;
        dst[idx] = f2bf(src[(size_t)m * 96 + n]);
    }
}

// ------------------------------------------------- block-diag channel mixing (MFMA)
#define WSTR 104
__global__ __launch_bounds__(256) void mix_mfma_kernel(const ushort* __restrict__ Xr,
        const ushort* __restrict__ Xi, const ushort* __restrict__ Wt,
        const float* __restrict__ bias, ushort* __restrict__ Or,
        ushort* __restrict__ Oi, int shrink) {
    int l = blockIdx.y;
    int bm = blockIdx.x * 128;
    int tid = threadIdx.x;
    int wv = tid >> 6, lane = tid & 63;
    int quad = lane >> 4, l16 = lane & 15;

    __shared__ __align__(16) ushort Wr_s[96 * WSTR];
    __shared__ __align__(16) ushort Wi_s[96 * WSTR];
    const ushort* wr_g = Wt + (size_t)l * 96 * 96;
    const ushort* wi_g = Wt + (size_t)(8 + l) * 96 * 96;
    for (int idx = tid; idx < (96 * 96) / 4; idx += 256) {
        int n = idx / 24, mq = idx - n * 24;
        *(uint2*)&Wr_s[n * WSTR + mq * 4] = *(const uint2*)(wr_g + (size_t)n * 96 + mq * 4);
        *(uint2*)&Wi_s[n * WSTR + mq * 4] = *(const uint2*)(wi_g + (size_t)n * 96 + mq * 4);
    }

    floatx4 accr[2][6], acci[2][6];
#pragma unroll
    for (int i = 0; i < 2; ++i)
#pragma unroll
        for (int j = 0; j < 6; ++j) {
            accr[i][j][0] = 0.f; accr[i][j][1] = 0.f; accr[i][j][2] = 0.f; accr[i][j][3] = 0.f;
            acci[i][j][0] = 0.f; acci[i][j][1] = 0.f; acci[i][j][2] = 0.f; acci[i][j][3] = 0.f;
        }

    int row = bm + wv * 32 + l16;
    const ushort* agr = Xr + (size_t)row * 768 + l * 96;
    const ushort* agi = Xi + (size_t)row * 768 + l * 96;
    __syncthreads();

#pragma unroll
    for (int ks = 0; ks < 3; ++ks) {
        int ko = ks * 32 + quad * 8;
        short8 ar0 = *(const short8*)(agr + ko);
        short8 ar1 = *(const short8*)(agr + (size_t)16 * 768 + ko);
        short8 ai0 = *(const short8*)(agi + ko);
        short8 ai1 = *(const short8*)(agi + (size_t)16 * 768 + ko);
        short8 an0 = neg8(ai0), an1 = neg8(ai1);
#pragma unroll
        for (int j = 0; j < 6; ++j) {
            short8 br = *(const short8*)&Wr_s[(j * 16 + l16) * WSTR + ko];
            short8 bi = *(const short8*)&Wi_s[(j * 16 + l16) * WSTR + ko];
            accr[0][j] = __builtin_amdgcn_mfma_f32_16x16x32_bf16(ar0, br, accr[0][j], 0, 0, 0);
            accr[0][j] = __builtin_amdgcn_mfma_f32_16x16x32_bf16(an0, bi, accr[0][j], 0, 0, 0);
            acci[0][j] = __builtin_amdgcn_mfma_f32_16x16x32_bf16(ar0, bi, acci[0][j], 0, 0, 0);
            acci[0][j] = __builtin_amdgcn_mfma_f32_16x16x32_bf16(ai0, br, acci[0][j], 0, 0, 0);
            accr[1][j] = __builtin_amdgcn_mfma_f32_16x16x32_bf16(ar1, br, accr[1][j], 0, 0, 0);
            accr[1][j] = __builtin_amdgcn_mfma_f32_16x16x32_bf16(an1, bi, accr[1][j], 0, 0, 0);
            acci[1][j] = __builtin_amdgcn_mfma_f32_16x16x32_bf16(ar1, bi, acci[1][j], 0, 0, 0);
            acci[1][j] = __builtin_amdgcn_mfma_f32_16x16x32_bf16(ai1, br, acci[1][j], 0, 0, 0);
        }
    }

#pragma unroll
    for (int i = 0; i < 2; ++i) {
        int row0 = bm + wv * 32 + i * 16 + quad * 4;
#pragma unroll
        for (int j = 0; j < 6; ++j) {
            int col = j * 16 + l16;
            float bvr = bias[l * 96 + col];
            float bvi = bias[768 + l * 96 + col];
#pragma unroll
            for (int r = 0; r < 4; ++r) {
                float vr = accr[i][j][r] + bvr;
                float vi = acci[i][j][r] + bvi;
                if (shrink) { vr = fmaxf(vr - LAMBDA_SS, 0.0f); vi = fmaxf(vi - LAMBDA_SS, 0.0f); }
                else        { vr = fmaxf(vr, 0.0f);             vi = fmaxf(vi, 0.0f); }
                size_t o = (size_t)(row0 + r) * 768 + l * 96 + col;
                Or[o] = f2bf(vr);
                Oi[o] = f2bf(vi);
            }
        }
    }
}

// ------------------------------------- fp32 -> bf16 transpose [R][C] -> [C][R]
__global__ __launch_bounds__(256) void transpose_kernel(const float* __restrict__ in,
        ushort* __restrict__ out, int R, int C) {
    __shared__ float tile[32][33];
    int c0 = blockIdx.x * 32, r0 = blockIdx.y * 32;
    int tx = threadIdx.x, ty = threadIdx.y;
    for (int j = 0; j < 32; j += 8)
        tile[ty + j][tx] = in[(size_t)(r0 + ty + j) * C + c0 + tx];
    __syncthreads();
    for (int j = 0; j < 32; j += 8)
        out[(size_t)(c0 + ty + j) * R + r0 + tx] = f2bf(tile[tx][ty + j]);
}

// --------------------------------------------------------------- MFMA GEMM (MLP)
#define GBM 128
#define GBN 128
#define GBK 32
__global__ __launch_bounds__(256) void gemm_bt_kernel(const ushort* __restrict__ A,
        const ushort* __restrict__ Bt, void* __restrict__ Cv, int M, int N, int K,
        const float* __restrict__ bias, const float* __restrict__ resid,
        int act, int out_f32) {
    __shared__ __align__(16) ushort As[GBM * GBK];
    __shared__ __align__(16) ushort Bs[GBN * GBK];
    int tid = threadIdx.x;
    int bm = blockIdx.y * GBM, bn = blockIdx.x * GBN;
    int wave = tid >> 6, lane = tid & 63;
    int wy = wave >> 1, wx = wave & 1;
    int quad = lane >> 4, l16 = lane & 15;
    int sr = tid >> 2;
    int sc = (tid & 3) * 8;
    const ushort* Ag = A + (size_t)(bm + sr) * K + sc;
    const ushort* Bg = Bt + (size_t)(bn + sr) * K + sc;

    floatx4 acc[4][4];
#pragma unroll
    for (int i = 0; i < 4; ++i)
#pragma unroll
        for (int j = 0; j < 4; ++j) { acc[i][j][0] = 0.f; acc[i][j][1] = 0.f; acc[i][j][2] = 0.f; acc[i][j][3] = 0.f; }

    for (int k0 = 0; k0 < K; k0 += GBK) {
        uint4 a0 = *(const uint4*)(Ag + k0);
        uint4 a1 = *(const uint4*)(Ag + (size_t)64 * K + k0);
        uint4 b0 = *(const uint4*)(Bg + k0);
        uint4 b1 = *(const uint4*)(Bg + (size_t)64 * K + k0);
        __syncthreads();
        *(uint4*)&As[sr * GBK + sc] = a0;
        *(uint4*)&As[(sr + 64) * GBK + sc] = a1;
        *(uint4*)&Bs[sr * GBK + sc] = b0;
        *(uint4*)&Bs[(sr + 64) * GBK + sc] = b1;
        __syncthreads();
        short8 af[4], bfv[4];
#pragma unroll
        for (int i = 0; i < 4; ++i)
            af[i] = *(const short8*)&As[(wy * 64 + i * 16 + l16) * GBK + quad * 8];
#pragma unroll
        for (int j = 0; j < 4; ++j)
            bfv[j] = *(const short8*)&Bs[(wx * 64 + j * 16 + l16) * GBK + quad * 8];
#pragma unroll
        for (int i = 0; i < 4; ++i)
#pragma unroll
            for (int j = 0; j < 4; ++j)
                acc[i][j] = __builtin_amdgcn_mfma_f32_16x16x32_bf16(af[i], bfv[j], acc[i][j], 0, 0, 0);
    }

#pragma unroll
    for (int i = 0; i < 4; ++i) {
        int row0 = bm + wy * 64 + i * 16 + quad * 4;
#pragma unroll
        for (int j = 0; j < 4; ++j) {
            int col = bn + wx * 64 + j * 16 + l16;
            float bv = bias ? bias[col] : 0.0f;
#pragma unroll
            for (int r = 0; r < 4; ++r) {
                float v = acc[i][j][r] + bv;
                if (act == 1) v = 0.5f * v * (1.0f + erff(v * 0.70710678118f));  // exact GELU
                size_t o = (size_t)(row0 + r) * N + col;
                if (out_f32) {
                    float vv = v + (resid ? resid[o] : 0.0f);
                    ((float*)Cv)[o] = vv;
                } else {
                    ((ushort*)Cv)[o] = f2bf(v);
                }
            }
        }
    }
}

// ---------------------------------------------------------------- launcher
extern "C" void kernel_launch(void* const* d_in, const int* in_sizes, int n_in,
                              void* d_out, int out_size, void* d_ws, size_t ws_size,
                              hipStream_t stream) {
    const float* x    = (const float*)d_in[0];
    const float* n1g  = (const float*)d_in[1];
    const float* n1b  = (const float*)d_in[2];
    const float* w1   = (const float*)d_in[3];
    const float* w2   = (const float*)d_in[4];
    const float* b1   = (const float*)d_in[5];
    const float* b2   = (const float*)d_in[6];
    const float* n2g  = (const float*)d_in[7];
    const float* n2b  = (const float*)d_in[8];
    const float* fc1w = (const float*)d_in[9];
    const float* fc1b = (const float*)d_in[10];
    const float* fc2w = (const float*)d_in[11];
    const float* fc2b = (const float*)d_in[12];
    float*  outf = (float*)d_out;
    ushort* outu = (ushort*)d_out;   // d_out (201 MB) doubles as bf16 scratch

    // ---- ws fixed region (shorts)
    ushort* ws  = (ushort*)d_ws;
    ushort* W1t = ws;                               // [3072][768]
    ushort* W2t = W1t + (size_t)3072 * 768;         // [768][3072]
    ushort* tw  = W2t + (size_t)768 * 3072;         // twiddles
    ushort* AR  = tw + TW_TOTAL;                    // arena (75,497,472 shorts)

    const size_t FSZ = (size_t)NPLANE * SFREQ;      // 25,362,432
    // arena aliases (time-disjoint):
    ushort* S1t = AR;                               // [256][768][256]
    ushort* FrT = AR;                               // [2][99072][128]
    ushort* FiT = AR + FSZ;
    ushort* Mr  = AR;                               // mix1 out [NPOS][768]
    ushort* Mi  = AR + FSZ;
    ushort* NrT = AR;                               // [2][99072][128]
    ushort* NiT = AR + FSZ;
    ushort* HrT = AR;                               // [256][768][160]
    ushort* HiT = AR + (size_t)256 * 768 * 160;
    ushort* Abf = AR;                               // LN2 out [65536][768]
    ushort* hid = AR + (size_t)65536 * 768;         // [8192][3072]

    // d_out aliases (time-disjoint):
    ushort* S1 = outu;                              // LN1 out [65536][768]
    ushort* Fr = outu;                              // [256][129][768]
    ushort* Fi = outu + FSZ;
    ushort* Gr = outu;                              // H-fwd out
    ushort* Gi = outu + FSZ;
    ushort* Nr = outu;                              // mix2 out
    ushort* Ni = outu + FSZ;
    ushort* Hr = outu;                              // H-inv out
    ushort* Hi = outu + FSZ;
    ushort* W1mix = outu + 2 * FSZ;                 // mix weights
    ushort* W2mix = W1mix + (size_t)2 * 8 * 96 * 96;

    // ---- weight / twiddle prep
    transpose_kernel<<<dim3(3072 / 32, 768 / 32), dim3(32, 8), 0, stream>>>(fc1w, W1t, 768, 3072);
    transpose_kernel<<<dim3(768 / 32, 3072 / 32), dim3(32, 8), 0, stream>>>(fc2w, W2t, 3072, 768);
    wmix_prep_kernel<<<16, 256, 0, stream>>>(w1, W1mix);
    wmix_prep_kernel<<<16, 256, 0, stream>>>(w2, W2mix);
    twiddle_prep_kernel<<<dim3(256, 3), 256, 0, stream>>>(tw);

    // ---- LN1: x -> S1 (bf16 in d_out)
    ln_kernel<<<65536, 256, 0, stream>>>(x, n1g, n1b, S1);

    // ---- W-fwd: transpose per plane, then fused dual GEMM (Fr, Fi in one pass)
    transpose_bf_kernel<<<dim3(768 / 32, 256 / 32, 256), dim3(32, 8), 0, stream>>>(
        S1, S1t, 256, 768, 256, (size_t)256 * 768, (size_t)768 * 256);
    dftc_kernel<<<dim3(768 / 128, 2, 256), 256, 0, stream>>>(
        tw + TW_WFC_H, tw + TW_WFC_L, tw + TW_WFS_H, tw + TW_WFS_L,
        S1t, S1t, Fr, Fi, WF, 768, 256, (size_t)768 * 256, (size_t)SFREQ, 0);

    // ---- H-fwd: transpose, then fused complex GEMM: Gr = C@Fr + S@Fi, Gi = C@Fi - S@Fr
    transpose_bf_kernel<<<dim3(SFREQ / 32, 128 / 32, 2), dim3(32, 8), 0, stream>>>(
        Fr, FrT, 128, SFREQ, 128, (size_t)128 * SFREQ, (size_t)128 * SFREQ);
    transpose_bf_kernel<<<dim3(SFREQ / 32, 128 / 32, 2), dim3(32, 8), 0, stream>>>(
        Fi, FiT, 128, SFREQ, 128, (size_t)128 * SFREQ, (size_t)128 * SFREQ);
    dftc_kernel<<<dim3(SFREQ / 128, 1, 2), 256, 0, stream>>>(
        tw + TW_HC_H, tw + TW_HC_L, tw + TW_HS_H, tw + TW_HS_L,
        FrT, FiT, Gr, Gi, 128, SFREQ, 128, (size_t)128 * SFREQ, (size_t)128 * SFREQ, 1);

    // ---- block-diagonal complex MLP (MFMA)
    mix_mfma_kernel<<<dim3(NPOS / 128, 8), 256, 0, stream>>>(Gr, Gi, W1mix, b1, Mr, Mi, 0);
    mix_mfma_kernel<<<dim3(NPOS / 128, 8), 256, 0, stream>>>(Mr, Mi, W2mix, b2, Nr, Ni, 1);

    // ---- H-inv: transpose, then fused complex GEMM with swapped operands:
    //      O1 = C@Ni + S@Nr = Hi ; O2 = C@Nr - S@Ni = Hr
    transpose_bf_kernel<<<dim3(SFREQ / 32, 128 / 32, 2), dim3(32, 8), 0, stream>>>(
        Nr, NrT, 128, SFREQ, 128, (size_t)128 * SFREQ, (size_t)128 * SFREQ);
    transpose_bf_kernel<<<dim3(SFREQ / 32, 128 / 32, 2), dim3(32, 8), 0, stream>>>(
        Ni, NiT, 128, SFREQ, 128, (size_t)128 * SFREQ, (size_t)128 * SFREQ);
    dftc_kernel<<<dim3(SFREQ / 128, 1, 2), 256, 0, stream>>>(
        tw + TW_HC_H, tw + TW_HC_L, tw + TW_HS_H, tw + TW_HS_L,
        NiT, NrT, Hi, Hr, 128, SFREQ, 128, (size_t)128 * SFREQ, (size_t)128 * SFREQ, 1);

    // ---- W-inv: transpose [p][129][768] -> [p][768][160] (K-pad), GEMM -> spatial fp32
    transpose_bf_kernel<<<dim3(768 / 32, 5, 256), dim3(32, 8), 0, stream>>>(
        Hr, HrT, WF, 768, 160, (size_t)SFREQ, (size_t)768 * 160);
    transpose_bf_kernel<<<dim3(768 / 32, 5, 256), dim3(32, 8), 0, stream>>>(
        Hi, HiT, WF, 768, 160, (size_t)SFREQ, (size_t)768 * 160);
    dftwi_kernel<<<dim3(768 / 128, 2, 256), 256, 0, stream>>>(
        tw + TW_WIC_H, tw + TW_WIC_L, tw + TW_WISN_H, tw + TW_WISN_L,
        HrT, HiT, outf, 256, 768, 160, (size_t)768 * 160, (size_t)256 * 768);

    // ---- LN2: d_out fp32 spatial -> Abf bf16 (ws)
    ln_kernel<<<65536, 256, 0, stream>>>(outf, n2g, n2b, Abf);

    // ---- MLP: gelu(h@fc1+b1) @ fc2 + b2 + residual -> d_out fp32
    const int CH = 8192;
    for (int c = 0; c < 8; ++c) {
        const ushort* Aln = Abf + (size_t)c * CH * 768;
        gemm_bt_kernel<<<dim3(3072 / GBN, CH / GBM), 256, 0, stream>>>(
            Aln, W1t, hid, CH, 3072, 768, fc1b, nullptr, 1, 0);
        gemm_bt_kernel<<<dim3(768 / GBN, CH / GBM), 256, 0, stream>>>(
            hid, W2t, outf + (size_t)c * CH * 768, CH, 768, 3072, fc2b,
            x + (size_t)c * CH * 768, 0, 1);
    }
}

// Round 4
// 2885.661 us; speedup vs baseline: 2.6483x; 1.0367x over previous
//
#include <hip/hip_runtime.h>
#include <math.h>

#define Hh 128
#define Ww 256
#define Dd 768
#define NPLANE 256            // B*H
#define WF 129                // W/2+1
#define SFREQ (WF*Dd)         // 99072
#define NPOS (2*Hh*WF)        // 33024
#define LAMBDA_SS 0.01f

typedef short short8 __attribute__((ext_vector_type(8)));
typedef float floatx4 __attribute__((ext_vector_type(4)));

__device__ __forceinline__ float bf2f(ushort u) {
    union { unsigned int i; float f; } v; v.i = ((unsigned int)u) << 16; return v.f;
}
__device__ __forceinline__ ushort f2bf(float f) {
    union { float f; unsigned int i; } v; v.f = f;
    unsigned int r = v.i + 0x7fffu + ((v.i >> 16) & 1u);   // RTNE
    return (ushort)(r >> 16);
}
__device__ __forceinline__ short8 neg8(short8 a) {        // flip bf16 sign bits
    union { short8 s; unsigned int u[4]; } v; v.s = a;
    v.u[0] ^= 0x80008000u; v.u[1] ^= 0x80008000u;
    v.u[2] ^= 0x80008000u; v.u[3] ^= 0x80008000u;
    return v.s;
}
// async global->LDS, 16 B per lane; lds dest must be wave-uniform (lane*16 auto)
__device__ __forceinline__ void gload_lds16(const ushort* g, ushort* l) {
    __builtin_amdgcn_global_load_lds(
        (const __attribute__((address_space(1))) unsigned int*)g,
        (__attribute__((address_space(3))) unsigned int*)l, 16, 0, 0);
}

// ------------------------------------------------- LayerNorm: fp32 in, bf16 out
__global__ __launch_bounds__(256) void ln_kernel(const float* __restrict__ x,
        const float* __restrict__ g, const float* __restrict__ b,
        ushort* __restrict__ out) {
    int row = blockIdx.x;
    int tid = threadIdx.x;
    const float* xr = x + (size_t)row * Dd;
    float v0 = xr[tid], v1 = xr[tid + 256], v2 = xr[tid + 512];
    __shared__ float red[256];
    red[tid] = v0 + v1 + v2;
    __syncthreads();
    for (int o = 128; o > 0; o >>= 1) { if (tid < o) red[tid] += red[tid + o]; __syncthreads(); }
    float mean = red[0] * (1.0f / 768.0f);
    __syncthreads();
    float d0 = v0 - mean, d1 = v1 - mean, d2 = v2 - mean;
    red[tid] = d0 * d0 + d1 * d1 + d2 * d2;
    __syncthreads();
    for (int o = 128; o > 0; o >>= 1) { if (tid < o) red[tid] += red[tid + o]; __syncthreads(); }
    float inv = rsqrtf(red[0] * (1.0f / 768.0f) + 1e-5f);
    ushort* orow = out + (size_t)row * Dd;
    orow[tid]       = f2bf(d0 * inv * g[tid]       + b[tid]);
    orow[tid + 256] = f2bf(d1 * inv * g[tid + 256] + b[tid + 256]);
    orow[tid + 512] = f2bf(d2 * inv * g[tid + 512] + b[tid + 512]);
}

// ---------------------------------------------------- twiddle tables (bf16 hi+lo)
#define TW_WFC_H  0
#define TW_WFC_L  65536
#define TW_WFS_H  131072
#define TW_WFS_L  196608
#define TW_HC_H   262144
#define TW_HC_L   278528
#define TW_HS_H   294912
#define TW_HS_L   311296
#define TW_HSN_H  327680
#define TW_HSN_L  344064
#define TW_WIC_H  360448
#define TW_WIC_L  401408
#define TW_WISN_H 442368
#define TW_WISN_L 483328
#define TW_TOTAL  524288

__device__ __forceinline__ void split_bf(float v, ushort* hi, ushort* lo) {
    ushort h = f2bf(v);
    *hi = h;
    *lo = f2bf(v - bf2f(h));
}

__global__ __launch_bounds__(256) void twiddle_prep_kernel(ushort* __restrict__ tw) {
    int fam = blockIdx.y;
    int idx = blockIdx.x * 256 + threadIdx.x;
    if (fam == 0) {                       // W-fwd: [wf][w] 256x256
        if (idx >= 65536) return;
        int wf = idx >> 8, w = idx & 255;
        float c = 0.0f, s = 0.0f;
        if (wf < WF) {
            int t = (w * wf) & 255;
            float ang = (float)t * (float)(2.0 * M_PI / 256.0);
            c = cosf(ang) * 0.0625f;
            s = -sinf(ang) * 0.0625f;
        }
        split_bf(c, &tw[TW_WFC_H + idx], &tw[TW_WFC_L + idx]);
        split_bf(s, &tw[TW_WFS_H + idx], &tw[TW_WFS_L + idx]);
    } else if (fam == 1) {                // H: [a][b] 128x128
        if (idx >= 16384) return;
        int a = idx >> 7, b = idx & 127;
        int t = (a * b) & 127;
        float ang = (float)t * (float)(2.0 * M_PI / 128.0);
        const float sc = 0.08838834764831845f;   // 1/sqrt(128)
        float c = cosf(ang) * sc, s = sinf(ang) * sc;
        split_bf(c,  &tw[TW_HC_H + idx],  &tw[TW_HC_L + idx]);
        split_bf(s,  &tw[TW_HS_H + idx],  &tw[TW_HS_L + idx]);
        split_bf(-s, &tw[TW_HSN_H + idx], &tw[TW_HSN_L + idx]);
    } else {                              // W-inv: [w][wf] 256x160
        if (idx >= 40960) return;
        int w = idx / 160, wf = idx - w * 160;
        float c = 0.0f, s = 0.0f;
        if (wf < WF) {
            int t = (w * wf) & 255;
            float ang = (float)t * (float)(2.0 * M_PI / 256.0);
            float wt = (wf == 0 || wf == 128) ? 0.5f : 1.0f;
            c = wt * cosf(ang) * 0.125f;
            s = -wt * sinf(ang) * 0.125f;
        }
        split_bf(c, &tw[TW_WIC_H + idx],  &tw[TW_WIC_L + idx]);
        split_bf(s, &tw[TW_WISN_H + idx], &tw[TW_WISN_L + idx]);
    }
}

// -------- batched bf16 transpose: in[z][R][C] -> out[z][C][Rpad], 64x64 tiles,
// full-cache-line loads AND stores; rows R..Rpad-1 zero-filled.
__global__ __launch_bounds__(256) void transpose_bf_kernel(const ushort* __restrict__ in,
        ushort* __restrict__ out, int R, int C, int Rpad, size_t inB, size_t outB) {
    __shared__ ushort tile[64][66];
    int z = blockIdx.z;
    int c0 = blockIdx.x * 64, r0 = blockIdx.y * 64;
    int tx = threadIdx.x, ty = threadIdx.y;      // (32, 8)
    const ushort* ip = in + (size_t)z * inB;
    ushort* op = out + (size_t)z * outB;
#pragma unroll
    for (int j = 0; j < 64; j += 8) {
        int r = r0 + ty + j;
        uint v = 0;
        if (r < R) v = *(const uint*)&ip[(size_t)r * C + c0 + tx * 2];
        *(uint*)&tile[ty + j][tx * 2] = v;
    }
    __syncthreads();
    int rr = tx * 2;
#pragma unroll
    for (int j = 0; j < 64; j += 8) {
        int c = ty + j;
        if (r0 + rr < Rpad) {
            union { uint u; ushort s[2]; } v;
            v.s[0] = tile[rr][c];
            v.s[1] = tile[rr + 1][c];
            *(uint*)&op[(size_t)(c0 + c) * Rpad + r0 + rr] = v.u;
        }
    }
}

// ---------------------------------------------- dual-output complex DFT GEMM
// mode 0: O1 = A1@B1^T ; O2 = A2@B1^T
// mode 1: O1 = A1@B1 + A2@B2 ; O2 = A1@B2 - A2@B1
// B staged async via global_load_lds (linear [row][32]); LDS-staged coalesced epilogue.
__global__ __launch_bounds__(256, 2) void dftc_kernel(
        const ushort* __restrict__ A1h, const ushort* __restrict__ A1l,
        const ushort* __restrict__ A2h, const ushort* __restrict__ A2l,
        const ushort* __restrict__ B1, const ushort* __restrict__ B2,
        ushort* __restrict__ O1, ushort* __restrict__ O2,
        int M, int N, int K, size_t strideB, size_t strideC, int mode) {
    __shared__ __align__(16) ushort smem[9216];   // 18432 B
    ushort* Bs1 = smem;                            // [128][32] during K-loop
    ushort* Bs2 = smem + 4096;
    int tid = threadIdx.x;
    int bn = blockIdx.x * 128, bm = blockIdx.y * 128;
    int z = blockIdx.z;
    int wv = tid >> 6, lane = tid & 63;
    int wy = wv >> 1, wx = wv & 1;
    int quad = lane >> 4, l16 = lane & 15;
    int sr = tid >> 2, sc = (tid & 3) * 8;

    const ushort* b1s = B1 + (size_t)z * strideB + (size_t)(bn + sr) * K + sc;
    const ushort* b2s = B2 + (size_t)z * strideB + (size_t)(bn + sr) * K + sc;

    size_t arow = (size_t)(bm + wy * 64 + l16) * K + quad * 8;
    const ushort* a1h_p = A1h + arow;
    const ushort* a1l_p = A1l + arow;
    const ushort* a2h_p = A2h + arow;
    const ushort* a2l_p = A2l + arow;

    floatx4 acc1[4][4], acc2[4][4];
#pragma unroll
    for (int i = 0; i < 4; ++i)
#pragma unroll
        for (int j = 0; j < 4; ++j) {
            acc1[i][j][0] = 0.f; acc1[i][j][1] = 0.f; acc1[i][j][2] = 0.f; acc1[i][j][3] = 0.f;
            acc2[i][j][0] = 0.f; acc2[i][j][1] = 0.f; acc2[i][j][2] = 0.f; acc2[i][j][3] = 0.f;
        }

    for (int k0 = 0; k0 < K; k0 += 32) {
        __syncthreads();
        gload_lds16(b1s + k0, Bs1 + wv * 512);
        gload_lds16(b1s + (size_t)64 * K + k0, Bs1 + 2048 + wv * 512);
        if (mode) {
            gload_lds16(b2s + k0, Bs2 + wv * 512);
            gload_lds16(b2s + (size_t)64 * K + k0, Bs2 + 2048 + wv * 512);
        }
        __syncthreads();
        short8 bf1[4], bf2v[4];
#pragma unroll
        for (int j = 0; j < 4; ++j)
            bf1[j] = *(const short8*)&Bs1[(wx * 64 + j * 16 + l16) * 32 + quad * 8];
        if (mode) {
#pragma unroll
            for (int j = 0; j < 4; ++j)
                bf2v[j] = *(const short8*)&Bs2[(wx * 64 + j * 16 + l16) * 32 + quad * 8];
        }
#pragma unroll
        for (int i = 0; i < 4; ++i) {
            size_t ao = (size_t)i * 16 * K + k0;
            short8 a1h_ = *(const short8*)(a1h_p + ao);
            short8 a1l_ = *(const short8*)(a1l_p + ao);
            short8 a2h_ = *(const short8*)(a2h_p + ao);
            short8 a2l_ = *(const short8*)(a2l_p + ao);
            if (mode) {
#pragma unroll
                for (int j = 0; j < 4; ++j) {
                    acc1[i][j] = __builtin_amdgcn_mfma_f32_16x16x32_bf16(a1h_, bf1[j], acc1[i][j], 0, 0, 0);
                    acc1[i][j] = __builtin_amdgcn_mfma_f32_16x16x32_bf16(a1l_, bf1[j], acc1[i][j], 0, 0, 0);
                    acc1[i][j] = __builtin_amdgcn_mfma_f32_16x16x32_bf16(a2h_, bf2v[j], acc1[i][j], 0, 0, 0);
                    acc1[i][j] = __builtin_amdgcn_mfma_f32_16x16x32_bf16(a2l_, bf2v[j], acc1[i][j], 0, 0, 0);
                }
                short8 n2h = neg8(a2h_), n2l = neg8(a2l_);
#pragma unroll
                for (int j = 0; j < 4; ++j) {
                    acc2[i][j] = __builtin_amdgcn_mfma_f32_16x16x32_bf16(a1h_, bf2v[j], acc2[i][j], 0, 0, 0);
                    acc2[i][j] = __builtin_amdgcn_mfma_f32_16x16x32_bf16(a1l_, bf2v[j], acc2[i][j], 0, 0, 0);
                    acc2[i][j] = __builtin_amdgcn_mfma_f32_16x16x32_bf16(n2h, bf1[j], acc2[i][j], 0, 0, 0);
                    acc2[i][j] = __builtin_amdgcn_mfma_f32_16x16x32_bf16(n2l, bf1[j], acc2[i][j], 0, 0, 0);
                }
            } else {
#pragma unroll
                for (int j = 0; j < 4; ++j) {
                    acc1[i][j] = __builtin_amdgcn_mfma_f32_16x16x32_bf16(a1h_, bf1[j], acc1[i][j], 0, 0, 0);
                    acc1[i][j] = __builtin_amdgcn_mfma_f32_16x16x32_bf16(a1l_, bf1[j], acc1[i][j], 0, 0, 0);
                    acc2[i][j] = __builtin_amdgcn_mfma_f32_16x16x32_bf16(a2h_, bf1[j], acc2[i][j], 0, 0, 0);
                    acc2[i][j] = __builtin_amdgcn_mfma_f32_16x16x32_bf16(a2l_, bf1[j], acc2[i][j], 0, 0, 0);
                }
            }
        }
    }

    // ---- epilogue: 64-row LDS staging [64][144], full-line coalesced stores
    int srow = tid >> 4;               // 0..15
    int schunk = (tid & 15) * 8;       // col start (shorts)
#pragma unroll
    for (int half = 0; half < 2; ++half) {
#pragma unroll
        for (int out = 0; out < 2; ++out) {
            __syncthreads();
            if (wy == half) {
#pragma unroll
                for (int i = 0; i < 4; ++i) {
                    int r0 = (i * 16 + quad * 4) * 144;
#pragma unroll
                    for (int j = 0; j < 4; ++j) {
                        int cc = wx * 64 + j * 16 + l16;
#pragma unroll
                        for (int r = 0; r < 4; ++r) {
                            float v = out ? acc2[i][j][r] : acc1[i][j][r];
                            smem[r0 + r * 144 + cc] = f2bf(v);
                        }
                    }
                }
            }
            __syncthreads();
            ushort* Optr = out ? O2 : O1;
#pragma unroll
            for (int p = 0; p < 4; ++p) {
                int row = p * 16 + srow;
                int grow = bm + half * 64 + row;
                if (grow < M) {
                    uint4 v = *(const uint4*)&smem[row * 144 + schunk];
                    *(uint4*)&Optr[(size_t)z * strideC + (size_t)grow * N + bn + schunk] = v;
                }
            }
        }
    }
}

// ---------------------------------------------- W-inverse DFT GEMM, fp32 out
// O = A1@B1 + A2@B2. Async B staging; LDS-staged coalesced fp32 stores.
__global__ __launch_bounds__(256, 2) void dftwi_kernel(
        const ushort* __restrict__ A1h, const ushort* __restrict__ A1l,
        const ushort* __restrict__ A2h, const ushort* __restrict__ A2l,
        const ushort* __restrict__ B1, const ushort* __restrict__ B2,
        float* __restrict__ O, int M, int N, int K, size_t strideB, size_t strideC) {
    __shared__ __align__(16) ushort smem[9216];   // 18432 B
    ushort* Bs1 = smem;
    ushort* Bs2 = smem + 4096;
    float* Csf = (float*)smem;                    // [32][132] during epilogue
    int tid = threadIdx.x;
    int bn = blockIdx.x * 128, bm = blockIdx.y * 128;
    int z = blockIdx.z;
    int wv = tid >> 6, lane = tid & 63;
    int wy = wv >> 1, wx = wv & 1;
    int quad = lane >> 4, l16 = lane & 15;
    int sr = tid >> 2, sc = (tid & 3) * 8;

    const ushort* b1s = B1 + (size_t)z * strideB + (size_t)(bn + sr) * K + sc;
    const ushort* b2s = B2 + (size_t)z * strideB + (size_t)(bn + sr) * K + sc;

    size_t arow = (size_t)(bm + wy * 64 + l16) * K + quad * 8;
    const ushort* a1h_p = A1h + arow;
    const ushort* a1l_p = A1l + arow;
    const ushort* a2h_p = A2h + arow;
    const ushort* a2l_p = A2l + arow;

    floatx4 acc[4][4];
#pragma unroll
    for (int i = 0; i < 4; ++i)
#pragma unroll
        for (int j = 0; j < 4; ++j) { acc[i][j][0] = 0.f; acc[i][j][1] = 0.f; acc[i][j][2] = 0.f; acc[i][j][3] = 0.f; }

    for (int k0 = 0; k0 < K; k0 += 32) {
        __syncthreads();
        gload_lds16(b1s + k0, Bs1 + wv * 512);
        gload_lds16(b1s + (size_t)64 * K + k0, Bs1 + 2048 + wv * 512);
        gload_lds16(b2s + k0, Bs2 + wv * 512);
        gload_lds16(b2s + (size_t)64 * K + k0, Bs2 + 2048 + wv * 512);
        __syncthreads();
        short8 bf1[4], bf2v[4];
#pragma unroll
        for (int j = 0; j < 4; ++j) {
            bf1[j] = *(const short8*)&Bs1[(wx * 64 + j * 16 + l16) * 32 + quad * 8];
            bf2v[j] = *(const short8*)&Bs2[(wx * 64 + j * 16 + l16) * 32 + quad * 8];
        }
#pragma unroll
        for (int i = 0; i < 4; ++i) {
            size_t ao = (size_t)i * 16 * K + k0;
            short8 a1h_ = *(const short8*)(a1h_p + ao);
            short8 a1l_ = *(const short8*)(a1l_p + ao);
            short8 a2h_ = *(const short8*)(a2h_p + ao);
            short8 a2l_ = *(const short8*)(a2l_p + ao);
#pragma unroll
            for (int j = 0; j < 4; ++j) {
                acc[i][j] = __builtin_amdgcn_mfma_f32_16x16x32_bf16(a1h_, bf1[j], acc[i][j], 0, 0, 0);
                acc[i][j] = __builtin_amdgcn_mfma_f32_16x16x32_bf16(a1l_, bf1[j], acc[i][j], 0, 0, 0);
                acc[i][j] = __builtin_amdgcn_mfma_f32_16x16x32_bf16(a2h_, bf2v[j], acc[i][j], 0, 0, 0);
                acc[i][j] = __builtin_amdgcn_mfma_f32_16x16x32_bf16(a2l_, bf2v[j], acc[i][j], 0, 0, 0);
            }
        }
    }

    // ---- epilogue: four 32-row quarters through LDS, full-line fp32 stores
    int srow8 = tid >> 5;              // 0..7
    int chunk = (tid & 31) * 4;        // float col
#pragma unroll
    for (int q = 0; q < 4; ++q) {
        __syncthreads();
        if (wy == (q >> 1)) {
            int ibase = (q & 1) * 2;
#pragma unroll
            for (int ii = 0; ii < 2; ++ii) {
                int i = ibase + ii;
                int r0 = (ii * 16 + quad * 4) * 132;
#pragma unroll
                for (int j = 0; j < 4; ++j) {
                    int cc = wx * 64 + j * 16 + l16;
#pragma unroll
                    for (int r = 0; r < 4; ++r)
                        Csf[r0 + r * 132 + cc] = acc[i][j][r];
                }
            }
        }
        __syncthreads();
#pragma unroll
        for (int p = 0; p < 4; ++p) {
            int row = p * 8 + srow8;
            uint4 v = *(const uint4*)&Csf[row * 132 + chunk];
            *(uint4*)&O[(size_t)z * strideC + (size_t)(bm + q * 32 + row) * N + bn + chunk] = v;
        }
    }
}

// ------------------------------------------ mix weight prep: fp32 [ri][l][m][n]
// -> bf16 Bt layout [ri][l][n][m]
__global__ __launch_bounds__(256) void wmix_prep_kernel(const float* __restrict__ w,
        ushort* __restrict__ wt) {
    int mat = blockIdx.x;
    const float* src = w + (size_t)mat * 96 * 96;
    ushort* dst = wt + (size_t)mat * 96 * 96;
    for (int idx = threadIdx.x; idx < 96 * 96; idx += 256) {
        int n = idx / 96, m = idx - n * 96;
        dst[idx] = f2bf(src[(size_t)m * 96 + n]);
    }
}

// ------------------------------------------------- block-diag channel mixing (MFMA)
#define WSTR 104
__global__ __launch_bounds__(256) void mix_mfma_kernel(const ushort* __restrict__ Xr,
        const ushort* __restrict__ Xi, const ushort* __restrict__ Wt,
        const float* __restrict__ bias, ushort* __restrict__ Or,
        ushort* __restrict__ Oi, int shrink) {
    int l = blockIdx.y;
    int bm = blockIdx.x * 128;
    int tid = threadIdx.x;
    int wv = tid >> 6, lane = tid & 63;
    int quad = lane >> 4, l16 = lane & 15;

    __shared__ __align__(16) ushort Wr_s[96 * WSTR];
    __shared__ __align__(16) ushort Wi_s[96 * WSTR];
    const ushort* wr_g = Wt + (size_t)l * 96 * 96;
    const ushort* wi_g = Wt + (size_t)(8 + l) * 96 * 96;
    for (int idx = tid; idx < (96 * 96) / 4; idx += 256) {
        int n = idx / 24, mq = idx - n * 24;
        *(uint2*)&Wr_s[n * WSTR + mq * 4] = *(const uint2*)(wr_g + (size_t)n * 96 + mq * 4);
        *(uint2*)&Wi_s[n * WSTR + mq * 4] = *(const uint2*)(wi_g + (size_t)n * 96 + mq * 4);
    }

    floatx4 accr[2][6], acci[2][6];
#pragma unroll
    for (int i = 0; i < 2; ++i)
#pragma unroll
        for (int j = 0; j < 6; ++j) {
            accr[i][j][0] = 0.f; accr[i][j][1] = 0.f; accr[i][j][2] = 0.f; accr[i][j][3] = 0.f;
            acci[i][j][0] = 0.f; acci[i][j][1] = 0.f; acci[i][j][2] = 0.f; acci[i][j][3] = 0.f;
        }

    int row = bm + wv * 32 + l16;
    const ushort* agr = Xr + (size_t)row * 768 + l * 96;
    const ushort* agi = Xi + (size_t)row * 768 + l * 96;
    __syncthreads();

#pragma unroll
    for (int ks = 0; ks < 3; ++ks) {
        int ko = ks * 32 + quad * 8;
        short8 ar0 = *(const short8*)(agr + ko);
        short8 ar1 = *(const short8*)(agr + (size_t)16 * 768 + ko);
        short8 ai0 = *(const short8*)(agi + ko);
        short8 ai1 = *(const short8*)(agi + (size_t)16 * 768 + ko);
        short8 an0 = neg8(ai0), an1 = neg8(ai1);
#pragma unroll
        for (int j = 0; j < 6; ++j) {
            short8 br = *(const short8*)&Wr_s[(j * 16 + l16) * WSTR + ko];
            short8 bi = *(const short8*)&Wi_s[(j * 16 + l16) * WSTR + ko];
            accr[0][j] = __builtin_amdgcn_mfma_f32_16x16x32_bf16(ar0, br, accr[0][j], 0, 0, 0);
            accr[0][j] = __builtin_amdgcn_mfma_f32_16x16x32_bf16(an0, bi, accr[0][j], 0, 0, 0);
            acci[0][j] = __builtin_amdgcn_mfma_f32_16x16x32_bf16(ar0, bi, acci[0][j], 0, 0, 0);
            acci[0][j] = __builtin_amdgcn_mfma_f32_16x16x32_bf16(ai0, br, acci[0][j], 0, 0, 0);
            accr[1][j] = __builtin_amdgcn_mfma_f32_16x16x32_bf16(ar1, br, accr[1][j], 0, 0, 0);
            accr[1][j] = __builtin_amdgcn_mfma_f32_16x16x32_bf16(an1, bi, accr[1][j], 0, 0, 0);
            acci[1][j] = __builtin_amdgcn_mfma_f32_16x16x32_bf16(ar1, bi, acci[1][j], 0, 0, 0);
            acci[1][j] = __builtin_amdgcn_mfma_f32_16x16x32_bf16(ai1, br, acci[1][j], 0, 0, 0);
        }
    }

#pragma unroll
    for (int i = 0; i < 2; ++i) {
        int row0 = bm + wv * 32 + i * 16 + quad * 4;
#pragma unroll
        for (int j = 0; j < 6; ++j) {
            int col = j * 16 + l16;
            float bvr = bias[l * 96 + col];
            float bvi = bias[768 + l * 96 + col];
#pragma unroll
            for (int r = 0; r < 4; ++r) {
                float vr = accr[i][j][r] + bvr;
                float vi = acci[i][j][r] + bvi;
                if (shrink) { vr = fmaxf(vr - LAMBDA_SS, 0.0f); vi = fmaxf(vi - LAMBDA_SS, 0.0f); }
                else        { vr = fmaxf(vr, 0.0f);             vi = fmaxf(vi, 0.0f); }
                size_t o = (size_t)(row0 + r) * 768 + l * 96 + col;
                Or[o] = f2bf(vr);
                Oi[o] = f2bf(vi);
            }
        }
    }
}

// ------------------------------------- fp32 -> bf16 transpose [R][C] -> [C][R]
__global__ __launch_bounds__(256) void transpose_kernel(const float* __restrict__ in,
        ushort* __restrict__ out, int R, int C) {
    __shared__ float tile[32][33];
    int c0 = blockIdx.x * 32, r0 = blockIdx.y * 32;
    int tx = threadIdx.x, ty = threadIdx.y;
    for (int j = 0; j < 32; j += 8)
        tile[ty + j][tx] = in[(size_t)(r0 + ty + j) * C + c0 + tx];
    __syncthreads();
    for (int j = 0; j < 32; j += 8)
        out[(size_t)(c0 + ty + j) * R + r0 + tx] = f2bf(tile[tx][ty + j]);
}

// --------------------------------------------------------------- MFMA GEMM (MLP)
#define GBM 128
#define GBN 128
#define GBK 32
__global__ __launch_bounds__(256) void gemm_bt_kernel(const ushort* __restrict__ A,
        const ushort* __restrict__ Bt, void* __restrict__ Cv, int M, int N, int K,
        const float* __restrict__ bias, const float* __restrict__ resid,
        int act, int out_f32) {
    __shared__ __align__(16) ushort As[GBM * GBK];
    __shared__ __align__(16) ushort Bs[GBN * GBK];
    int tid = threadIdx.x;
    int bm = blockIdx.y * GBM, bn = blockIdx.x * GBN;
    int wave = tid >> 6, lane = tid & 63;
    int wy = wave >> 1, wx = wave & 1;
    int quad = lane >> 4, l16 = lane & 15;
    int sr = tid >> 2;
    int sc = (tid & 3) * 8;
    const ushort* Ag = A + (size_t)(bm + sr) * K + sc;
    const ushort* Bg = Bt + (size_t)(bn + sr) * K + sc;
    ushort* AsW  = As + wave * 512;
    ushort* AsW2 = As + 2048 + wave * 512;
    ushort* BsW  = Bs + wave * 512;
    ushort* BsW2 = Bs + 2048 + wave * 512;

    floatx4 acc[4][4];
#pragma unroll
    for (int i = 0; i < 4; ++i)
#pragma unroll
        for (int j = 0; j < 4; ++j) { acc[i][j][0] = 0.f; acc[i][j][1] = 0.f; acc[i][j][2] = 0.f; acc[i][j][3] = 0.f; }

    for (int k0 = 0; k0 < K; k0 += GBK) {
        __syncthreads();
        gload_lds16(Ag + k0, AsW);
        gload_lds16(Ag + (size_t)64 * K + k0, AsW2);
        gload_lds16(Bg + k0, BsW);
        gload_lds16(Bg + (size_t)64 * K + k0, BsW2);
        __syncthreads();
        short8 af[4], bfv[4];
#pragma unroll
        for (int i = 0; i < 4; ++i)
            af[i] = *(const short8*)&As[(wy * 64 + i * 16 + l16) * GBK + quad * 8];
#pragma unroll
        for (int j = 0; j < 4; ++j)
            bfv[j] = *(const short8*)&Bs[(wx * 64 + j * 16 + l16) * GBK + quad * 8];
#pragma unroll
        for (int i = 0; i < 4; ++i)
#pragma unroll
            for (int j = 0; j < 4; ++j)
                acc[i][j] = __builtin_amdgcn_mfma_f32_16x16x32_bf16(af[i], bfv[j], acc[i][j], 0, 0, 0);
    }

#pragma unroll
    for (int i = 0; i < 4; ++i) {
        int row0 = bm + wy * 64 + i * 16 + quad * 4;
#pragma unroll
        for (int j = 0; j < 4; ++j) {
            int col = bn + wx * 64 + j * 16 + l16;
            float bv = bias ? bias[col] : 0.0f;
#pragma unroll
            for (int r = 0; r < 4; ++r) {
                float v = acc[i][j][r] + bv;
                if (act == 1) v = 0.5f * v * (1.0f + erff(v * 0.70710678118f));  // exact GELU
                size_t o = (size_t)(row0 + r) * N + col;
                if (out_f32) {
                    float vv = v + (resid ? resid[o] : 0.0f);
                    ((float*)Cv)[o] = vv;
                } else {
                    ((ushort*)Cv)[o] = f2bf(v);
                }
            }
        }
    }
}

// ---------------------------------------------------------------- launcher
extern "C" void kernel_launch(void* const* d_in, const int* in_sizes, int n_in,
                              void* d_out, int out_size, void* d_ws, size_t ws_size,
                              hipStream_t stream) {
    const float* x    = (const float*)d_in[0];
    const float* n1g  = (const float*)d_in[1];
    const float* n1b  = (const float*)d_in[2];
    const float* w1   = (const float*)d_in[3];
    const float* w2   = (const float*)d_in[4];
    const float* b1   = (const float*)d_in[5];
    const float* b2   = (const float*)d_in[6];
    const float* n2g  = (const float*)d_in[7];
    const float* n2b  = (const float*)d_in[8];
    const float* fc1w = (const float*)d_in[9];
    const float* fc1b = (const float*)d_in[10];
    const float* fc2w = (const float*)d_in[11];
    const float* fc2b = (const float*)d_in[12];
    float*  outf = (float*)d_out;
    ushort* outu = (ushort*)d_out;

    // ---- ws fixed region (shorts)
    ushort* ws  = (ushort*)d_ws;
    ushort* W1t = ws;                               // [3072][768]
    ushort* W2t = W1t + (size_t)3072 * 768;         // [768][3072]
    ushort* tw  = W2t + (size_t)768 * 3072;         // twiddles
    ushort* AR  = tw + TW_TOTAL;                    // arena

    const size_t FSZ = (size_t)NPLANE * SFREQ;      // 25,362,432
    // arena aliases (time-disjoint):
    ushort* S1t = AR;                               // [256][768][256]
    ushort* FrT = AR;                               // [2][99072][128]
    ushort* FiT = AR + FSZ;
    ushort* Mr  = AR;                               // mix1 out [NPOS][768]
    ushort* Mi  = AR + FSZ;
    ushort* NrT = AR;
    ushort* NiT = AR + FSZ;
    ushort* HrT = AR;                               // [256][768][160]
    ushort* HiT = AR + (size_t)256 * 768 * 160;
    ushort* Abf = AR;                               // LN2 out [65536][768]
    ushort* hid = AR + (size_t)65536 * 768;         // [8192][3072]

    // d_out aliases (time-disjoint):
    ushort* S1 = outu;
    ushort* Fr = outu;
    ushort* Fi = outu + FSZ;
    ushort* Gr = outu;
    ushort* Gi = outu + FSZ;
    ushort* Nr = outu;
    ushort* Ni = outu + FSZ;
    ushort* Hr = outu;
    ushort* Hi = outu + FSZ;
    ushort* W1mix = outu + 2 * FSZ;
    ushort* W2mix = W1mix + (size_t)2 * 8 * 96 * 96;

    // ---- weight / twiddle prep
    transpose_kernel<<<dim3(3072 / 32, 768 / 32), dim3(32, 8), 0, stream>>>(fc1w, W1t, 768, 3072);
    transpose_kernel<<<dim3(768 / 32, 3072 / 32), dim3(32, 8), 0, stream>>>(fc2w, W2t, 3072, 768);
    wmix_prep_kernel<<<16, 256, 0, stream>>>(w1, W1mix);
    wmix_prep_kernel<<<16, 256, 0, stream>>>(w2, W2mix);
    twiddle_prep_kernel<<<dim3(256, 3), 256, 0, stream>>>(tw);

    // ---- LN1: x -> S1 (bf16 in d_out)
    ln_kernel<<<65536, 256, 0, stream>>>(x, n1g, n1b, S1);

    // ---- W-fwd: transpose per plane, then fused dual GEMM (Fr, Fi in one pass)
    transpose_bf_kernel<<<dim3(768 / 64, 256 / 64, 256), dim3(32, 8), 0, stream>>>(
        S1, S1t, 256, 768, 256, (size_t)256 * 768, (size_t)768 * 256);
    dftc_kernel<<<dim3(768 / 128, 2, 256), 256, 0, stream>>>(
        tw + TW_WFC_H, tw + TW_WFC_L, tw + TW_WFS_H, tw + TW_WFS_L,
        S1t, S1t, Fr, Fi, WF, 768, 256, (size_t)768 * 256, (size_t)SFREQ, 0);

    // ---- H-fwd: transpose, then fused complex GEMM: Gr = C@Fr + S@Fi, Gi = C@Fi - S@Fr
    transpose_bf_kernel<<<dim3(SFREQ / 64, 2, 2), dim3(32, 8), 0, stream>>>(
        Fr, FrT, 128, SFREQ, 128, (size_t)128 * SFREQ, (size_t)128 * SFREQ);
    transpose_bf_kernel<<<dim3(SFREQ / 64, 2, 2), dim3(32, 8), 0, stream>>>(
        Fi, FiT, 128, SFREQ, 128, (size_t)128 * SFREQ, (size_t)128 * SFREQ);
    dftc_kernel<<<dim3(SFREQ / 128, 1, 2), 256, 0, stream>>>(
        tw + TW_HC_H, tw + TW_HC_L, tw + TW_HS_H, tw + TW_HS_L,
        FrT, FiT, Gr, Gi, 128, SFREQ, 128, (size_t)128 * SFREQ, (size_t)128 * SFREQ, 1);

    // ---- block-diagonal complex MLP (MFMA)
    mix_mfma_kernel<<<dim3(NPOS / 128, 8), 256, 0, stream>>>(Gr, Gi, W1mix, b1, Mr, Mi, 0);
    mix_mfma_kernel<<<dim3(NPOS / 128, 8), 256, 0, stream>>>(Mr, Mi, W2mix, b2, Nr, Ni, 1);

    // ---- H-inv: transpose, then fused complex GEMM (swapped operands)
    transpose_bf_kernel<<<dim3(SFREQ / 64, 2, 2), dim3(32, 8), 0, stream>>>(
        Nr, NrT, 128, SFREQ, 128, (size_t)128 * SFREQ, (size_t)128 * SFREQ);
    transpose_bf_kernel<<<dim3(SFREQ / 64, 2, 2), dim3(32, 8), 0, stream>>>(
        Ni, NiT, 128, SFREQ, 128, (size_t)128 * SFREQ, (size_t)128 * SFREQ);
    dftc_kernel<<<dim3(SFREQ / 128, 1, 2), 256, 0, stream>>>(
        tw + TW_HC_H, tw + TW_HC_L, tw + TW_HS_H, tw + TW_HS_L,
        NiT, NrT, Hi, Hr, 128, SFREQ, 128, (size_t)128 * SFREQ, (size_t)128 * SFREQ, 1);

    // ---- W-inv: transpose [p][129][768] -> [p][768][160] (K-pad), GEMM -> spatial fp32
    transpose_bf_kernel<<<dim3(768 / 64, 3, 256), dim3(32, 8), 0, stream>>>(
        Hr, HrT, WF, 768, 160, (size_t)SFREQ, (size_t)768 * 160);
    transpose_bf_kernel<<<dim3(768 / 64, 3, 256), dim3(32, 8), 0, stream>>>(
        Hi, HiT, WF, 768, 160, (size_t)SFREQ, (size_t)768 * 160);
    dftwi_kernel<<<dim3(768 / 128, 2, 256), 256, 0, stream>>>(
        tw + TW_WIC_H, tw + TW_WIC_L, tw + TW_WISN_H, tw + TW_WISN_L,
        HrT, HiT, outf, 256, 768, 160, (size_t)768 * 160, (size_t)256 * 768);

    // ---- LN2: d_out fp32 spatial -> Abf bf16 (ws)
    ln_kernel<<<65536, 256, 0, stream>>>(outf, n2g, n2b, Abf);

    // ---- MLP: gelu(h@fc1+b1) @ fc2 + b2 + residual -> d_out fp32
    const int CH = 8192;
    for (int c = 0; c < 8; ++c) {
        const ushort* Aln = Abf + (size_t)c * CH * 768;
        gemm_bt_kernel<<<dim3(3072 / GBN, CH / GBM), 256, 0, stream>>>(
            Aln, W1t, hid, CH, 3072, 768, fc1b, nullptr, 1, 0);
        gemm_bt_kernel<<<dim3(768 / GBN, CH / GBM), 256, 0, stream>>>(
            hid, W2t, outf + (size_t)c * CH * 768, CH, 768, 3072, fc2b,
            x + (size_t)c * CH * 768, 0, 1);
    }
}